// Round 2
// baseline (461.590 us; speedup 1.0000x reference)
//
#include <hip/hip_runtime.h>
#include <math.h>

typedef __bf16 bf16;
typedef __bf16 bf16x4 __attribute__((ext_vector_type(4)));
typedef __bf16 bf16x8 __attribute__((ext_vector_type(8)));
typedef float f32x4 __attribute__((ext_vector_type(4)));
typedef unsigned short u16;
typedef u16 u16x2 __attribute__((ext_vector_type(2)));

#define LOG2E 1.4426950408889634f

__device__ __forceinline__ float b2f(u16 b) {
  return (float)__builtin_bit_cast(bf16, b);
}

// ---------------------------------------------------------------------------
// dtype sniff (wave-parallel): packed-bf16 words have bits14..7 = bf16
// exponent (~[118,130]); f32 words have uniform mantissa bits there.
// ---------------------------------------------------------------------------
__global__ void sniff_k(const unsigned* __restrict__ xw_, int* __restrict__ flag) {
  int lane = threadIdx.x;  // 64 threads
  int c = 0;
#pragma unroll
  for (int j = 0; j < 4; j++) {
    unsigned e = (xw_[lane * 4 + j] >> 7) & 0xFFu;
    c += (e >= 100u && e <= 140u) ? 1 : 0;
  }
#pragma unroll
  for (int d = 1; d < 64; d <<= 1) c += __shfl_xor(c, d);
  if (lane == 0) *flag = (c >= 150) ? 1 : 0;
}

__global__ __launch_bounds__(256) void canon_big_k(const void* __restrict__ src,
                                                   bf16* __restrict__ dst,
                                                   const int* __restrict__ flag) {
  int i = (blockIdx.x * 256 + threadIdx.x) * 8;
  if (*flag) {
    *(bf16x8*)&dst[i] = *(const bf16x8*)((const bf16*)src + i);
  } else {
    const float* s = (const float*)src + i;
    bf16x8 v;
#pragma unroll
    for (int j = 0; j < 8; j++) v[j] = (bf16)s[j];
    *(bf16x8*)&dst[i] = v;
  }
}

struct CanonArgs {
  const void* src[13];
  bf16* dst[13];
  int n[13];
};

__global__ __launch_bounds__(256) void canon_small_k(CanonArgs a,
                                                     const int* __restrict__ flag) {
  int ti = blockIdx.y;
  int i = blockIdx.x * 256 + threadIdx.x;
  if (i >= a.n[ti]) return;
  if (*flag)
    a.dst[ti][i] = ((const bf16*)a.src[ti])[i];
  else
    a.dst[ti][i] = (bf16)((const float*)a.src[ti])[i];
}

// ---------------------------------------------------------------------------
// Fused rpe+mask planes, exp2-domain:
// rpem[type][h][q][m] = rel_bias[rel_index[q*512+m]][h]*log2e + (masked?-100*log2e:0)
// type bits: 4=d-boundary window (wd==1), 2=h-boundary (wh==7), 1=w-boundary.
// ---------------------------------------------------------------------------
__global__ __launch_bounds__(256) void rpem_k(const int* __restrict__ ridx,
                                              const bf16* __restrict__ rbias,
                                              bf16* __restrict__ rpem) {
  int t = blockIdx.x * 256 + threadIdx.x;  // 2^21 threads, 4 m-values each
  int m0 = (t & 127) * 4, q = (t >> 7) & 511, h = (t >> 16) & 3, ty = t >> 18;
  int qd = q >> 6, qh = (q >> 3) & 7, qw = q & 7;
  int4 ri = *(const int4*)&ridx[q * 512 + m0];
  const int rv[4] = {ri.x, ri.y, ri.z, ri.w};
  bf16x4 o;
#pragma unroll
  for (int j = 0; j < 4; j++) {
    int m = m0 + j;
    int md = m >> 6, mh = (m >> 3) & 7, mw = m & 7;
    bool diff = ((ty & 4) && ((qd < 4) != (md < 4))) ||
                ((ty & 2) && ((qh < 4) != (mh < 4))) ||
                ((ty & 1) && ((qw < 4) != (mw < 4)));
    float v = (float)rbias[rv[j] * 4 + h] * LOG2E;
    o[j] = (bf16)(v + (diff ? -144.2695041f : 0.f));
  }
  *(bf16x4*)&rpem[(size_t)t * 4] = o;
}

// ---------------------------------------------------------------------------
// LayerNorm. ROLL=1: read x at roll(-4)+window-partition source, write window
// layout. ROLL=0: linear in/out. One wave per token (C=128), packed u32 I/O.
// ---------------------------------------------------------------------------
template <int ROLL>
__global__ __launch_bounds__(256) void ln_k(const bf16* __restrict__ x,
                                            const bf16* __restrict__ g,
                                            const bf16* __restrict__ bsh,
                                            bf16* __restrict__ out) {
  int wave = threadIdx.x >> 6, lane = threadIdx.x & 63;
  int tok = blockIdx.x * 4 + wave;
  size_t src;
  if (ROLL) {
    int win = tok >> 9, pos = tok & 511;
    int rd = (win >> 6) * 8 + (pos >> 6);
    int rh = ((win >> 3) & 7) * 8 + ((pos >> 3) & 7);
    int rw = (win & 7) * 8 + (pos & 7);
    int od = (rd + 4) & 15, oh = (rh + 4) & 63, ow = (rw + 4) & 63;
    src = (size_t)((od * 64 + oh) * 64 + ow) * 128;
  } else {
    src = (size_t)tok * 128;
  }
  int ch = lane * 2;
  u16x2 xv = *(const u16x2*)(x + src + ch);
  float f0 = b2f(xv[0]), f1 = b2f(xv[1]);
  float s = f0 + f1, sq = f0 * f0 + f1 * f1;
#pragma unroll
  for (int d = 1; d < 64; d <<= 1) {
    s += __shfl_xor(s, d);
    sq += __shfl_xor(sq, d);
  }
  float mean = s * (1.f / 128.f);
  float var = sq * (1.f / 128.f) - mean * mean;
  float rstd = rsqrtf(fmaxf(var, 0.f) + 1e-5f);
  u16x2 gv = *(const u16x2*)(g + ch), bv = *(const u16x2*)(bsh + ch);
  u16x2 ov;
  ov[0] = __builtin_bit_cast(u16, (bf16)((f0 - mean) * rstd * b2f(gv[0]) + b2f(bv[0])));
  ov[1] = __builtin_bit_cast(u16, (bf16)((f1 - mean) * rstd * b2f(gv[1]) + b2f(bv[1])));
  *(u16x2*)(out + (size_t)tok * 128 + ch) = ov;
}

// ---------------------------------------------------------------------------
// bf16 MFMA GEMM: C[M,N] = A[M,K] @ B[N,K]^T + bias[N] (+ epilogue)
// BM in {128,64}, BN=128, BK=64. A-tile register double-buffer across
// K-chunks. VGPR->ds_write staging (global_load_lds raced in R3).
// EPI: 0 = qkv (q scale*log2e, head-major scatter), 1 = proj (win-rev+roll+
//      resid), 2 = mlp1 (tanh-gelu, exp2-based), 3 = mlp2 (resid; flagged out)
// ---------------------------------------------------------------------------
template <int EPI, int BM, int N_, int K_>
__global__ __launch_bounds__(256) void gemm_k(const bf16* __restrict__ A,
                                              const bf16* __restrict__ B,
                                              const bf16* __restrict__ bias,
                                              void* __restrict__ outv,
                                              const bf16* __restrict__ resid,
                                              const int* __restrict__ flag) {
  __shared__ __align__(16) u16 As[BM * 72];
  __shared__ __align__(16) u16 Bs[128 * 72];
  const int t = threadIdx.x;
  const int wave = t >> 6, lane = t & 63, l15 = lane & 15, quad = lane >> 4;
  const int m0 = blockIdx.x * BM, n0 = blockIdx.y * 128;
  constexpr int MI = BM / 32;       // m-frags per wave
  constexpr int PA = BM / 32;       // A staging passes
  int fl = 0;
  if constexpr (EPI == 3) fl = *flag;
  f32x4 acc[MI][4] = {};
  const int wr = (wave >> 1) * (BM / 2), wc = (wave & 1) * 64;
  const int srow = t >> 3, scol = (t & 7) * 8;  // 32 rows per 256-thread pass
  constexpr int NC = K_ / 64;
  bf16x8 avA[PA], avB[PA];
#pragma unroll
  for (int p = 0; p < PA; p++) {
    int row = p * 32 + srow;
    avA[p] = *(const bf16x8*)(A + (size_t)(m0 + row) * K_ + scol);
  }
#pragma unroll
  for (int c = 0; c < NC; c++) {
    const bf16x8* av = (c & 1) ? avB : avA;
    bf16x8* avN = (c & 1) ? avA : avB;
    if (c + 1 < NC) {  // prefetch next A chunk (overlaps this chunk's compute)
#pragma unroll
      for (int p = 0; p < PA; p++) {
        int row = p * 32 + srow;
        avN[p] = *(const bf16x8*)(A + (size_t)(m0 + row) * K_ + (c + 1) * 64 + scol);
      }
    }
    bf16x8 bv[4];
#pragma unroll
    for (int p = 0; p < 4; p++) {
      int row = p * 32 + srow;
      bv[p] = *(const bf16x8*)(B + (size_t)(n0 + row) * K_ + c * 64 + scol);
    }
    __syncthreads();  // prev iter's LDS reads done
#pragma unroll
    for (int p = 0; p < PA; p++)
      *(bf16x8*)&As[(p * 32 + srow) * 72 + scol] = av[p];
#pragma unroll
    for (int p = 0; p < 4; p++)
      *(bf16x8*)&Bs[(p * 32 + srow) * 72 + scol] = bv[p];
    __syncthreads();
#pragma unroll
    for (int ks = 0; ks < 2; ks++) {
      bf16x8 a[MI], b[4];
#pragma unroll
      for (int i = 0; i < MI; i++)
        a[i] = *(const bf16x8*)&As[(wr + i * 16 + l15) * 72 + ks * 32 + quad * 8];
#pragma unroll
      for (int j = 0; j < 4; j++)
        b[j] = *(const bf16x8*)&Bs[(wc + j * 16 + l15) * 72 + ks * 32 + quad * 8];
#pragma unroll
      for (int i = 0; i < MI; i++)
#pragma unroll
        for (int j = 0; j < 4; j++)
          acc[i][j] =
              __builtin_amdgcn_mfma_f32_16x16x32_bf16(a[i], b[j], acc[i][j], 0, 0, 0);
    }
  }
  // q scale folded with log2e for exp2-domain softmax downstream
  const float qscale = 0.17677669529663687f * LOG2E;
#pragma unroll
  for (int i = 0; i < MI; i++) {
#pragma unroll
    for (int r = 0; r < 4; r++) {
      int tok = m0 + wr + i * 16 + quad * 4 + r;
      size_t obase = 0;
      if constexpr (EPI == 1) {
        int win = tok >> 9, pos = tok & 511;
        int rd = (win >> 6) * 8 + (pos >> 6);
        int rh = ((win >> 3) & 7) * 8 + ((pos >> 3) & 7);
        int rw = (win & 7) * 8 + (pos & 7);
        int od = (rd + 4) & 15, oh = (rh + 4) & 63, ow = (rw + 4) & 63;
        obase = (size_t)((od * 64 + oh) * 64 + ow) * 128;
      } else if constexpr (EPI != 0) {
        obase = (size_t)tok * N_;
      }
#pragma unroll
      for (int j = 0; j < 4; j++) {
        int gn = n0 + wc + j * 16 + l15;
        float v = acc[i][j][r] + (float)bias[gn];
        if constexpr (EPI == 0) {
          int tensor = gn >> 7, c = gn & 127, head = c >> 5, d = c & 31;
          if (tensor == 0) v *= qscale;
          int win = tok >> 9, pos = tok & 511;
          size_t off = ((((size_t)tensor * 4 + head) * 128 + win) * 512 + pos) * 32 + d;
          ((bf16*)outv)[off] = (bf16)v;
        } else if constexpr (EPI == 1) {
          v += (float)resid[obase + gn];
          ((bf16*)outv)[obase + gn] = (bf16)v;
        } else if constexpr (EPI == 2) {
          // tanh-GELU via native exp2: g = v - v/(exp2(u2)+1)
          float v2 = v * v;
          float u2 = v * (2.30220806f + 0.10294323f * v2);
          float e2 = exp2f(u2);
          float rcp = __builtin_amdgcn_rcpf(e2 + 1.f);
          v = v - v * rcp;
          ((bf16*)outv)[obase + gn] = (bf16)v;
        } else {
          v += (float)resid[obase + gn];
          if (fl)
            ((bf16*)outv)[obase + gn] = (bf16)v;
          else
            ((float*)outv)[obase + gn] = v;
        }
      }
    }
  }
}

// ---------------------------------------------------------------------------
// Fused window attention, S^T formulation, exp2-domain, BARRIER-FREE K-loop.
// R8: 8-wave blocks (512 thr) sharing one V^T tile -> LDS exactly 64 KB ->
// 2 blocks/CU = 16 waves/CU (was 12). Pad-free XOR-swizzled LDS
// (byte ^= (row&7)<<4) for both sVt and per-wave sP: <=2-way conflicts.
// kt loop fully unrolled (prefetch rotation becomes SSA renaming).
// No running max (scores structurally bounded; mask -100*log2e -> exp2==0).
// ---------------------------------------------------------------------------
__global__ __launch_bounds__(512) void attn_k(const bf16* __restrict__ qkv,
                                              const bf16* __restrict__ rpem,
                                              bf16* __restrict__ att) {
  __shared__ __align__(16) bf16 sVt[32 * 512];   // V^T [d][key], swizzled, 32 KB
  __shared__ __align__(16) bf16 sP[8][32 * 64];  // per-wave P^T, swizzled, 32 KB
  const int t = threadIdx.x;
  const int p = blockIdx.x;  // [win_hi:4][head:2][qh:1][win_lo:3]
  const int win = ((p >> 6) << 3) | (p & 7);
  const int mid = (p >> 3) & 7;
  const int head = mid >> 1, qh = mid & 1;
  const int wave = t >> 6, lane = t & 63, l15 = lane & 15, quad = lane >> 4;

  const int wd = win >> 6, wh = (win >> 3) & 7, ww = win & 7;
  const int type = ((wd == 1) << 2) | ((wh == 7) << 1) | (ww == 7);

  const size_t hw32 = (size_t)512 * 32;
  const bf16* qp = qkv + ((size_t)(0 * 4 + head) * 128 + win) * hw32;
  const bf16* kp = qkv + ((size_t)(1 * 4 + head) * 128 + win) * hw32;
  const bf16* vp = qkv + ((size_t)(2 * 4 + head) * 128 + win) * hw32;
  const bf16* rpeh = rpem + (size_t)(type * 4 + head) * 512 * 512;
  const int qbase = qh * 256 + wave * 32;

  {  // stage full V^T once (512 threads), XOR-swizzled u32 writes
    int kpi = t >> 3, dblk = (t & 7) * 4;
    char* sb = (char*)sVt;
#pragma unroll
    for (int kb = 0; kb < 4; kb++) {
      const bf16* v0 = vp + (size_t)(kb * 128 + 2 * kpi) * 32 + dblk;
      bf16x4 a = *(const bf16x4*)v0;
      bf16x4 b = *(const bf16x4*)(v0 + 32);
      int keyw = kb * 64 + kpi;
#pragma unroll
      for (int dd = 0; dd < 4; dd++) {
        int row = dblk + dd;
        unsigned wv = (unsigned)__builtin_bit_cast(u16, a[dd]) |
                      ((unsigned)__builtin_bit_cast(u16, b[dd]) << 16);
        *(unsigned*)(sb + ((row * 1024 + keyw * 4) ^ ((row & 7) << 4))) = wv;
      }
    }
  }

  // Q fragments (B operand): lane n=l15 -> query, k=quad*8+j -> d
  bf16x8 qa[2];
#pragma unroll
  for (int nt = 0; nt < 2; nt++)
    qa[nt] = *(const bf16x8*)(qp + (size_t)(qbase + nt * 16 + l15) * 32 + quad * 8);

  // prefetch kt=0 K-frags + rpe-frags (global, independent of LDS)
  bf16x8 kb[4];
  bf16x4 rv[4][2];
#pragma unroll
  for (int mt = 0; mt < 4; mt++) {
    kb[mt] = *(const bf16x8*)(kp + (size_t)(mt * 16 + l15) * 32 + quad * 8);
#pragma unroll
    for (int nt = 0; nt < 2; nt++)
      rv[mt][nt] = *(const bf16x4*)(rpeh + (size_t)(qbase + nt * 16 + l15) * 512 +
                                    mt * 16 + quad * 4);
  }

  __syncthreads();  // the ONLY block-wide barrier

  f32x4 O[2][2] = {};        // O^T tiles [dm][nt]
  float ls[2] = {0.f, 0.f};  // per-lane partial denominators
  char* pw = (char*)sP[wave];
  const char* sv = (const char*)sVt;
  const int swz = (l15 & 7) << 4;  // row-XOR (same for row and row+16)

#pragma unroll
  for (int kt = 0; kt < 8; kt++) {
    // issue next tile's loads early (no barrier in loop -> they pipeline)
    bf16x8 kbn[4];
    bf16x4 rvn[4][2];
    if (kt < 7) {
#pragma unroll
      for (int mt = 0; mt < 4; mt++) {
        kbn[mt] = *(const bf16x8*)(kp +
                                   (size_t)((kt + 1) * 64 + mt * 16 + l15) * 32 +
                                   quad * 8);
#pragma unroll
        for (int nt = 0; nt < 2; nt++)
          rvn[mt][nt] =
              *(const bf16x4*)(rpeh + (size_t)(qbase + nt * 16 + l15) * 512 +
                               (kt + 1) * 64 + mt * 16 + quad * 4);
      }
    }
    // S^T = K·Q^T with C initialized to fused rpe+mask (pure load)
    f32x4 S[4][2];
#pragma unroll
    for (int mt = 0; mt < 4; mt++)
#pragma unroll
      for (int nt = 0; nt < 2; nt++) {
        f32x4 c;
#pragma unroll
        for (int r = 0; r < 4; r++) c[r] = (float)rv[mt][nt][r];
        S[mt][nt] = __builtin_amdgcn_mfma_f32_16x16x32_bf16(kb[mt], qa[nt], c, 0, 0, 0);
      }
    // exp2 + partial sum + P store (swizzled b64 writes)
#pragma unroll
    for (int nt = 0; nt < 2; nt++)
#pragma unroll
      for (int mt = 0; mt < 4; mt++) {
        bf16x4 pv;
#pragma unroll
        for (int r = 0; r < 4; r++) {
          float pe = exp2f(S[mt][nt][r]);
          ls[nt] += pe;
          pv[r] = (bf16)pe;
        }
        *(bf16x4*)(pw + (((nt * 16 + l15) * 128 + mt * 32 + quad * 8) ^ swz)) = pv;
      }
    // O^T += V^T · P  (sVt read-only; pw per-wave)
#pragma unroll
    for (int s = 0; s < 2; s++) {
      int vc = kt * 128 + s * 64 + quad * 16;  // byte col into V^T row
      int pc = s * 64 + quad * 16;             // byte col into P row
      bf16x8 va0 = *(const bf16x8*)(sv + ((l15 * 1024 + vc) ^ swz));
      bf16x8 va1 = *(const bf16x8*)(sv + (((16 + l15) * 1024 + vc) ^ swz));
      bf16x8 pb0 = *(const bf16x8*)(pw + ((l15 * 128 + pc) ^ swz));
      bf16x8 pb1 = *(const bf16x8*)(pw + (((16 + l15) * 128 + pc) ^ swz));
      O[0][0] = __builtin_amdgcn_mfma_f32_16x16x32_bf16(va0, pb0, O[0][0], 0, 0, 0);
      O[0][1] = __builtin_amdgcn_mfma_f32_16x16x32_bf16(va0, pb1, O[0][1], 0, 0, 0);
      O[1][0] = __builtin_amdgcn_mfma_f32_16x16x32_bf16(va1, pb0, O[1][0], 0, 0, 0);
      O[1][1] = __builtin_amdgcn_mfma_f32_16x16x32_bf16(va1, pb1, O[1][1], 0, 0, 0);
    }
    // rotate prefetch registers (SSA-renamed under full unroll)
#pragma unroll
    for (int mt = 0; mt < 4; mt++) {
      kb[mt] = kbn[mt];
      rv[mt][0] = rvn[mt][0];
      rv[mt][1] = rvn[mt][1];
    }
  }
  // epilogue: reduce denominators across quads once, then scaled O writes
#pragma unroll
  for (int nt = 0; nt < 2; nt++) {
    float l = ls[nt];
    l += __shfl_xor(l, 16);
    l += __shfl_xor(l, 32);
    float inv = __builtin_amdgcn_rcpf(l);
    int q = qbase + nt * 16 + l15;
#pragma unroll
    for (int dm = 0; dm < 2; dm++) {
      bf16x4 o;
#pragma unroll
      for (int r = 0; r < 4; r++) o[r] = (bf16)(O[dm][nt][r] * inv);
      *(bf16x4*)(att + ((size_t)win * 512 + q) * 128 + head * 32 + dm * 16 +
                 quad * 4) = o;
    }
  }
}

// ---------------------------------------------------------------------------
extern "C" void kernel_launch(void* const* d_in, const int* in_sizes, int n_in,
                              void* d_out, int out_size, void* d_ws,
                              size_t ws_size, hipStream_t stream) {
  const int* rel_index = (const int*)d_in[2];
  char* w = (char*)d_ws;

  int* flag = (int*)w;
  bf16* rb_c = (bf16*)(w + (64ull << 10));
  bf16* qw_c = (bf16*)(w + (128ull << 10));
  bf16* pw_c = (bf16*)(w + (256ull << 10));
  bf16* w1_c = (bf16*)(w + (320ull << 10));
  bf16* w2_c = (bf16*)(w + (512ull << 10));
  bf16* qb_c = (bf16*)(w + (704ull << 10));
  bf16* pb_c = (bf16*)(w + (708ull << 10));
  bf16* g1_c = (bf16*)(w + (712ull << 10));
  bf16* b1n_c = (bf16*)(w + (716ull << 10));
  bf16* g2_c = (bf16*)(w + (720ull << 10));
  bf16* b2n_c = (bf16*)(w + (724ull << 10));
  bf16* mb1_c = (bf16*)(w + (728ull << 10));
  bf16* mb2_c = (bf16*)(w + (732ull << 10));
  bf16* x_c = (bf16*)(w + (1ull << 20));    // [1,17) MB
  bf16* xw = (bf16*)(w + (17ull << 20));    // [17,33) MB; reused: att, h2
  bf16* qkvb = (bf16*)(w + (33ull << 20));  // [33,97) MB; reused: a1
  bf16* x2 = (bf16*)(w + (99ull << 20));    // [99,115) MB; rpem lives here
  bf16* rpem = x2;  // 16 MiB fused rpe+mask planes; dead before proj writes x2
  bf16* att = xw;
  bf16* h2 = xw;
  bf16* a1 = qkvb;

  sniff_k<<<1, 64, 0, stream>>>((const unsigned*)d_in[0], flag);
  canon_big_k<<<4096, 256, 0, stream>>>(d_in[0], x_c, flag);

  CanonArgs ca;
  const int srcidx[13] = {3, 4, 5, 6, 7, 8, 9, 10, 11, 12, 13, 14, 15};
  bf16* dsts[13] = {rb_c, qw_c, qb_c, pw_c, pb_c, g1_c, b1n_c,
                    g2_c, b2n_c, w1_c, mb1_c, w2_c, mb2_c};
  for (int i = 0; i < 13; i++) {
    ca.src[i] = d_in[srcidx[i]];
    ca.dst[i] = dsts[i];
    ca.n[i] = in_sizes[srcidx[i]];
  }
  canon_small_k<<<dim3(256, 13), 256, 0, stream>>>(ca, flag);

  rpem_k<<<8192, 256, 0, stream>>>(rel_index, rb_c, rpem);
  ln_k<1><<<16384, 256, 0, stream>>>(x_c, g1_c, b1n_c, xw);
  gemm_k<0, 128, 384, 128><<<dim3(512, 3), 256, 0, stream>>>(xw, qw_c, qb_c,
                                                             qkvb, nullptr, flag);
  attn_k<<<1024, 512, 0, stream>>>(qkvb, rpem, att);
  gemm_k<1, 64, 128, 128><<<dim3(1024, 1), 256, 0, stream>>>(att, pw_c, pb_c,
                                                             x2, x_c, flag);
  ln_k<0><<<16384, 256, 0, stream>>>(x2, g2_c, b2n_c, h2);
  gemm_k<2, 128, 512, 128><<<dim3(512, 4), 256, 0, stream>>>(h2, w1_c, mb1_c,
                                                             a1, nullptr, flag);
  gemm_k<3, 64, 128, 512><<<dim3(1024, 1), 256, 0, stream>>>(a1, w2_c, mb2_c,
                                                             d_out, x2, flag);
}

// Round 3
// 437.543 us; speedup vs baseline: 1.0550x; 1.0550x over previous
//
#include <hip/hip_runtime.h>
#include <math.h>

typedef __bf16 bf16;
typedef __bf16 bf16x4 __attribute__((ext_vector_type(4)));
typedef __bf16 bf16x8 __attribute__((ext_vector_type(8)));
typedef float f32x4 __attribute__((ext_vector_type(4)));
typedef unsigned short u16;
typedef u16 u16x2 __attribute__((ext_vector_type(2)));

#define LOG2E 1.4426950408889634f

__device__ __forceinline__ float b2f(u16 b) {
  return (float)__builtin_bit_cast(bf16, b);
}

// ---------------------------------------------------------------------------
// dtype sniff (wave-parallel): packed-bf16 words have bits14..7 = bf16
// exponent (~[118,130]); f32 words have uniform mantissa bits there.
// ---------------------------------------------------------------------------
__global__ void sniff_k(const unsigned* __restrict__ xw_, int* __restrict__ flag) {
  int lane = threadIdx.x;  // 64 threads
  int c = 0;
#pragma unroll
  for (int j = 0; j < 4; j++) {
    unsigned e = (xw_[lane * 4 + j] >> 7) & 0xFFu;
    c += (e >= 100u && e <= 140u) ? 1 : 0;
  }
#pragma unroll
  for (int d = 1; d < 64; d <<= 1) c += __shfl_xor(c, d);
  if (lane == 0) *flag = (c >= 150) ? 1 : 0;
}

__global__ __launch_bounds__(256) void canon_big_k(const void* __restrict__ src,
                                                   bf16* __restrict__ dst,
                                                   const int* __restrict__ flag) {
  int i = (blockIdx.x * 256 + threadIdx.x) * 8;
  if (*flag) {
    *(bf16x8*)&dst[i] = *(const bf16x8*)((const bf16*)src + i);
  } else {
    const float* s = (const float*)src + i;
    bf16x8 v;
#pragma unroll
    for (int j = 0; j < 8; j++) v[j] = (bf16)s[j];
    *(bf16x8*)&dst[i] = v;
  }
}

struct CanonArgs {
  const void* src[13];
  bf16* dst[13];
  int n[13];
};

__global__ __launch_bounds__(256) void canon_small_k(CanonArgs a,
                                                     const int* __restrict__ flag) {
  int ti = blockIdx.y;
  int i = blockIdx.x * 256 + threadIdx.x;
  if (i >= a.n[ti]) return;
  if (*flag)
    a.dst[ti][i] = ((const bf16*)a.src[ti])[i];
  else
    a.dst[ti][i] = (bf16)((const float*)a.src[ti])[i];
}

// ---------------------------------------------------------------------------
// Fused rpe+mask planes, exp2-domain:
// rpem[type][h][q][m] = rel_bias[rel_index[q*512+m]][h]*log2e + (masked?-100*log2e:0)
// type bits: 4=d-boundary window (wd==1), 2=h-boundary (wh==7), 1=w-boundary.
// ---------------------------------------------------------------------------
__global__ __launch_bounds__(256) void rpem_k(const int* __restrict__ ridx,
                                              const bf16* __restrict__ rbias,
                                              bf16* __restrict__ rpem) {
  int t = blockIdx.x * 256 + threadIdx.x;  // 2^21 threads, 4 m-values each
  int m0 = (t & 127) * 4, q = (t >> 7) & 511, h = (t >> 16) & 3, ty = t >> 18;
  int qd = q >> 6, qh = (q >> 3) & 7, qw = q & 7;
  int4 ri = *(const int4*)&ridx[q * 512 + m0];
  const int rv[4] = {ri.x, ri.y, ri.z, ri.w};
  bf16x4 o;
#pragma unroll
  for (int j = 0; j < 4; j++) {
    int m = m0 + j;
    int md = m >> 6, mh = (m >> 3) & 7, mw = m & 7;
    bool diff = ((ty & 4) && ((qd < 4) != (md < 4))) ||
                ((ty & 2) && ((qh < 4) != (mh < 4))) ||
                ((ty & 1) && ((qw < 4) != (mw < 4)));
    float v = (float)rbias[rv[j] * 4 + h] * LOG2E;
    o[j] = (bf16)(v + (diff ? -144.2695041f : 0.f));
  }
  *(bf16x4*)&rpem[(size_t)t * 4] = o;
}

// ---------------------------------------------------------------------------
// LayerNorm. ROLL=1: read x at roll(-4)+window-partition source, write window
// layout. ROLL=0: linear in/out. One wave per token (C=128), packed u32 I/O.
// ---------------------------------------------------------------------------
template <int ROLL>
__global__ __launch_bounds__(256) void ln_k(const bf16* __restrict__ x,
                                            const bf16* __restrict__ g,
                                            const bf16* __restrict__ bsh,
                                            bf16* __restrict__ out) {
  int wave = threadIdx.x >> 6, lane = threadIdx.x & 63;
  int tok = blockIdx.x * 4 + wave;
  size_t src;
  if (ROLL) {
    int win = tok >> 9, pos = tok & 511;
    int rd = (win >> 6) * 8 + (pos >> 6);
    int rh = ((win >> 3) & 7) * 8 + ((pos >> 3) & 7);
    int rw = (win & 7) * 8 + (pos & 7);
    int od = (rd + 4) & 15, oh = (rh + 4) & 63, ow = (rw + 4) & 63;
    src = (size_t)((od * 64 + oh) * 64 + ow) * 128;
  } else {
    src = (size_t)tok * 128;
  }
  int ch = lane * 2;
  u16x2 xv = *(const u16x2*)(x + src + ch);
  float f0 = b2f(xv[0]), f1 = b2f(xv[1]);
  float s = f0 + f1, sq = f0 * f0 + f1 * f1;
#pragma unroll
  for (int d = 1; d < 64; d <<= 1) {
    s += __shfl_xor(s, d);
    sq += __shfl_xor(sq, d);
  }
  float mean = s * (1.f / 128.f);
  float var = sq * (1.f / 128.f) - mean * mean;
  float rstd = rsqrtf(fmaxf(var, 0.f) + 1e-5f);
  u16x2 gv = *(const u16x2*)(g + ch), bv = *(const u16x2*)(bsh + ch);
  u16x2 ov;
  ov[0] = __builtin_bit_cast(u16, (bf16)((f0 - mean) * rstd * b2f(gv[0]) + b2f(bv[0])));
  ov[1] = __builtin_bit_cast(u16, (bf16)((f1 - mean) * rstd * b2f(gv[1]) + b2f(bv[1])));
  *(u16x2*)(out + (size_t)tok * 128 + ch) = ov;
}

// ---------------------------------------------------------------------------
// bf16 MFMA GEMM: C[M,N] = A[M,K] @ B[N,K]^T + bias[N] (+ epilogue)
// BM in {128,64}, BN=128, BK=64. A-tile register double-buffer across
// K-chunks. VGPR->ds_write staging.
// R9: vectorized epilogue — C tile staged through (dead) As/Bs LDS as
// bf16 [BM][136], re-read row-major as b128, stores/resid-loads are
// bf16x8/float4 (VMEM per thread 64->8 stores, 64->8 resid loads).
// EPI: 0 = qkv (q scale*log2e, head-major scatter), 1 = proj (win-rev+roll+
//      resid), 2 = mlp1 (tanh-gelu, exp2-based), 3 = mlp2 (resid; flagged out)
// ---------------------------------------------------------------------------
template <int EPI, int BM, int N_, int K_>
__global__ __launch_bounds__(256) void gemm_k(const bf16* __restrict__ A,
                                              const bf16* __restrict__ B,
                                              const bf16* __restrict__ bias,
                                              void* __restrict__ outv,
                                              const bf16* __restrict__ resid,
                                              const int* __restrict__ flag) {
  __shared__ __align__(16) u16 SMEM[BM * 72 + 128 * 72];
  u16* As = SMEM;
  u16* Bs = SMEM + BM * 72;
  const int t = threadIdx.x;
  const int wave = t >> 6, lane = t & 63, l15 = lane & 15, quad = lane >> 4;
  const int m0 = blockIdx.x * BM, n0 = blockIdx.y * 128;
  constexpr int MI = BM / 32;       // m-frags per wave
  constexpr int PA = BM / 32;       // A staging passes
  int fl = 0;
  if constexpr (EPI == 3) fl = *flag;
  f32x4 acc[MI][4] = {};
  const int wr = (wave >> 1) * (BM / 2), wc = (wave & 1) * 64;
  const int srow = t >> 3, scol = (t & 7) * 8;  // 32 rows per 256-thread pass
  constexpr int NC = K_ / 64;
  bf16x8 avA[PA], avB[PA];
#pragma unroll
  for (int p = 0; p < PA; p++) {
    int row = p * 32 + srow;
    avA[p] = *(const bf16x8*)(A + (size_t)(m0 + row) * K_ + scol);
  }
#pragma unroll
  for (int c = 0; c < NC; c++) {
    const bf16x8* av = (c & 1) ? avB : avA;
    bf16x8* avN = (c & 1) ? avA : avB;
    if (c + 1 < NC) {  // prefetch next A chunk (overlaps this chunk's compute)
#pragma unroll
      for (int p = 0; p < PA; p++) {
        int row = p * 32 + srow;
        avN[p] = *(const bf16x8*)(A + (size_t)(m0 + row) * K_ + (c + 1) * 64 + scol);
      }
    }
    bf16x8 bv[4];
#pragma unroll
    for (int p = 0; p < 4; p++) {
      int row = p * 32 + srow;
      bv[p] = *(const bf16x8*)(B + (size_t)(n0 + row) * K_ + c * 64 + scol);
    }
    __syncthreads();  // prev iter's LDS reads done
#pragma unroll
    for (int p = 0; p < PA; p++)
      *(bf16x8*)&As[(p * 32 + srow) * 72 + scol] = av[p];
#pragma unroll
    for (int p = 0; p < 4; p++)
      *(bf16x8*)&Bs[(p * 32 + srow) * 72 + scol] = bv[p];
    __syncthreads();
#pragma unroll
    for (int ks = 0; ks < 2; ks++) {
      bf16x8 a[MI], b[4];
#pragma unroll
      for (int i = 0; i < MI; i++)
        a[i] = *(const bf16x8*)&As[(wr + i * 16 + l15) * 72 + ks * 32 + quad * 8];
#pragma unroll
      for (int j = 0; j < 4; j++)
        b[j] = *(const bf16x8*)&Bs[(wc + j * 16 + l15) * 72 + ks * 32 + quad * 8];
#pragma unroll
      for (int i = 0; i < MI; i++)
#pragma unroll
        for (int j = 0; j < 4; j++)
          acc[i][j] =
              __builtin_amdgcn_mfma_f32_16x16x32_bf16(a[i], b[j], acc[i][j], 0, 0, 0);
    }
  }
  // -------- epilogue: LDS transpose-staging, vectorized global I/O --------
  __syncthreads();  // last chunk's LDS reads done; reuse SMEM as C tile
  u16* Cs = SMEM;   // [BM][136] bf16
  const float qscale = 0.17677669529663687f * LOG2E;
#pragma unroll
  for (int i = 0; i < MI; i++)
#pragma unroll
    for (int j = 0; j < 4; j++) {
      int c = wc + j * 16 + l15;
      float bj = (float)bias[n0 + c];
#pragma unroll
      for (int r = 0; r < 4; r++) {
        float v = acc[i][j][r] + bj;
        if constexpr (EPI == 0) {
          if (n0 == 0) v *= qscale;  // tensor==0 (q) is uniform per block
        }
        if constexpr (EPI == 2) {
          // tanh-GELU via native exp2: g = v - v/(exp2(u2)+1)
          float v2 = v * v;
          float u2 = v * (2.30220806f + 0.10294323f * v2);
          float e2 = exp2f(u2);
          float rcp = __builtin_amdgcn_rcpf(e2 + 1.f);
          v = v - v * rcp;
        }
        Cs[(wr + i * 16 + quad * 4 + r) * 136 + c] =
            __builtin_bit_cast(u16, (bf16)v);
      }
    }
  __syncthreads();
  // read phase: thread -> (row, col-chunk); all global I/O vectorized
  constexpr int TPR = 256 / BM;    // threads per row
  constexpr int CPT = 128 / TPR;   // cols per thread
  const int row = t / TPR, chb = (t % TPR) * CPT;
  const int tok = m0 + row;
  size_t obase = 0;
  if constexpr (EPI == 1) {
    int win = tok >> 9, pos = tok & 511;
    int rd = (win >> 6) * 8 + (pos >> 6);
    int rh = ((win >> 3) & 7) * 8 + ((pos >> 3) & 7);
    int rw = (win & 7) * 8 + (pos & 7);
    int od = (rd + 4) & 15, oh = (rh + 4) & 63, ow = (rw + 4) & 63;
    obase = (size_t)((od * 64 + oh) * 64 + ow) * 128;
  } else if constexpr (EPI == 2) {
    obase = (size_t)tok * N_ + n0;
  } else if constexpr (EPI == 3) {
    obase = (size_t)tok * N_;
  }
#pragma unroll
  for (int cc = 0; cc < CPT / 8; cc++) {
    int c0 = chb + cc * 8;
    bf16x8 cv = *(const bf16x8*)&Cs[row * 136 + c0];
    if constexpr (EPI == 0) {
      int win = tok >> 9, pos = tok & 511;
      int tensor = n0 >> 7, head = c0 >> 5, d = c0 & 31;
      size_t off =
          ((((size_t)tensor * 4 + head) * 128 + win) * 512 + pos) * 32 + d;
      *(bf16x8*)((bf16*)outv + off) = cv;
    } else if constexpr (EPI == 1) {
      bf16x8 rv8 = *(const bf16x8*)(resid + obase + c0);
      bf16x8 o;
#pragma unroll
      for (int e = 0; e < 8; e++) o[e] = (bf16)((float)cv[e] + (float)rv8[e]);
      *(bf16x8*)((bf16*)outv + obase + c0) = o;
    } else if constexpr (EPI == 2) {
      *(bf16x8*)((bf16*)outv + obase + c0) = cv;
    } else {
      bf16x8 rv8 = *(const bf16x8*)(resid + obase + c0);
      float fo[8];
#pragma unroll
      for (int e = 0; e < 8; e++) fo[e] = (float)cv[e] + (float)rv8[e];
      if (fl) {
        bf16x8 o;
#pragma unroll
        for (int e = 0; e < 8; e++) o[e] = (bf16)fo[e];
        *(bf16x8*)((bf16*)outv + obase + c0) = o;
      } else {
        f32x4 o0 = {fo[0], fo[1], fo[2], fo[3]};
        f32x4 o1 = {fo[4], fo[5], fo[6], fo[7]};
        *(f32x4*)((float*)outv + obase + c0) = o0;
        *(f32x4*)((float*)outv + obase + c0 + 4) = o1;
      }
    }
  }
}

// ---------------------------------------------------------------------------
// Fused window attention, S^T formulation, exp2-domain, BARRIER-FREE K-loop.
// R9: 8-wave shared-V (2 blocks/CU, 16 waves/CU), NO software prefetch and
// #pragma unroll 1 (R2's 128-VGPR spill post-mortem), denominator computed
// on the MFMA pipe via an all-ones A-frag against the P fragments (removes
// 32 VALU adds/kt + epilogue shuffles). XOR-swizzled pad-free LDS.
// ---------------------------------------------------------------------------
__global__ __launch_bounds__(512, 4) void attn_k(const bf16* __restrict__ qkv,
                                                 const bf16* __restrict__ rpem,
                                                 bf16* __restrict__ att) {
  __shared__ __align__(16) bf16 sVt[32 * 512];   // V^T [d][key], swizzled, 32 KB
  __shared__ __align__(16) bf16 sP[8][32 * 64];  // per-wave P^T, swizzled, 32 KB
  const int t = threadIdx.x;
  const int p = blockIdx.x;  // [win_hi:4][head:2][qh:1][win_lo:3]
  const int win = ((p >> 6) << 3) | (p & 7);
  const int mid = (p >> 3) & 7;
  const int head = mid >> 1, qh = mid & 1;
  const int wave = t >> 6, lane = t & 63, l15 = lane & 15, quad = lane >> 4;

  const int wd = win >> 6, wh = (win >> 3) & 7, ww = win & 7;
  const int type = ((wd == 1) << 2) | ((wh == 7) << 1) | (ww == 7);

  const size_t hw32 = (size_t)512 * 32;
  const bf16* qp = qkv + ((size_t)(0 * 4 + head) * 128 + win) * hw32;
  const bf16* kp = qkv + ((size_t)(1 * 4 + head) * 128 + win) * hw32;
  const bf16* vp = qkv + ((size_t)(2 * 4 + head) * 128 + win) * hw32;
  const bf16* rpeh = rpem + (size_t)(type * 4 + head) * 512 * 512;
  const int qbase = qh * 256 + wave * 32;

  {  // stage full V^T once (512 threads), XOR-swizzled u32 writes
    int kpi = t >> 3, dblk = (t & 7) * 4;
    char* sb = (char*)sVt;
#pragma unroll
    for (int kb = 0; kb < 4; kb++) {
      const bf16* v0 = vp + (size_t)(kb * 128 + 2 * kpi) * 32 + dblk;
      bf16x4 a = *(const bf16x4*)v0;
      bf16x4 b = *(const bf16x4*)(v0 + 32);
      int keyw = kb * 64 + kpi;
#pragma unroll
      for (int dd = 0; dd < 4; dd++) {
        int row = dblk + dd;
        unsigned wv = (unsigned)__builtin_bit_cast(u16, a[dd]) |
                      ((unsigned)__builtin_bit_cast(u16, b[dd]) << 16);
        *(unsigned*)(sb + ((row * 1024 + keyw * 4) ^ ((row & 7) << 4))) = wv;
      }
    }
  }

  // Q fragments (B operand): lane n=l15 -> query, k=quad*8+j -> d
  bf16x8 qa[2];
#pragma unroll
  for (int nt = 0; nt < 2; nt++)
    qa[nt] = *(const bf16x8*)(qp + (size_t)(qbase + nt * 16 + l15) * 32 + quad * 8);

  // all-ones A-frag for the denominator MFMA
  bf16x8 ones;
#pragma unroll
  for (int e = 0; e < 8; e++) ones[e] = (bf16)1.0f;

  __syncthreads();  // the ONLY block-wide barrier

  f32x4 O[2][2] = {};   // O^T tiles [dm][nt]
  f32x4 O2[2] = {};     // denominator tiles (all rows identical)
  char* pw = (char*)sP[wave];
  const char* sv = (const char*)sVt;
  const int swz = (l15 & 7) << 4;  // row-XOR (same for row and row+16)

#pragma unroll 1
  for (int kt = 0; kt < 8; kt++) {
    // K frags + fused rpe+mask C-init (in-loop loads; 16 waves/CU hide them)
    bf16x8 kb[4];
    bf16x4 rv[4][2];
#pragma unroll
    for (int mt = 0; mt < 4; mt++) {
      kb[mt] = *(const bf16x8*)(kp + (size_t)(kt * 64 + mt * 16 + l15) * 32 +
                                quad * 8);
#pragma unroll
      for (int nt = 0; nt < 2; nt++)
        rv[mt][nt] =
            *(const bf16x4*)(rpeh + (size_t)(qbase + nt * 16 + l15) * 512 +
                             kt * 64 + mt * 16 + quad * 4);
    }
    // S^T = K·Q^T with C initialized to fused rpe+mask (pure load)
    f32x4 S[4][2];
#pragma unroll
    for (int mt = 0; mt < 4; mt++)
#pragma unroll
      for (int nt = 0; nt < 2; nt++) {
        f32x4 c;
#pragma unroll
        for (int r = 0; r < 4; r++) c[r] = (float)rv[mt][nt][r];
        S[mt][nt] = __builtin_amdgcn_mfma_f32_16x16x32_bf16(kb[mt], qa[nt], c, 0, 0, 0);
      }
    // exp2 + P store (swizzled b64 writes); no per-lane sums (MFMA does it)
#pragma unroll
    for (int nt = 0; nt < 2; nt++)
#pragma unroll
      for (int mt = 0; mt < 4; mt++) {
        bf16x4 pv;
#pragma unroll
        for (int r = 0; r < 4; r++) pv[r] = (bf16)exp2f(S[mt][nt][r]);
        *(bf16x4*)(pw + (((nt * 16 + l15) * 128 + mt * 32 + quad * 8) ^ swz)) = pv;
      }
    // O^T += V^T · P ; denominator += ones · P  (sVt read-only; pw per-wave)
#pragma unroll
    for (int s = 0; s < 2; s++) {
      int vc = kt * 128 + s * 64 + quad * 16;  // byte col into V^T row
      int pc = s * 64 + quad * 16;             // byte col into P row
      bf16x8 va0 = *(const bf16x8*)(sv + ((l15 * 1024 + vc) ^ swz));
      bf16x8 va1 = *(const bf16x8*)(sv + (((16 + l15) * 1024 + vc) ^ swz));
      bf16x8 pb0 = *(const bf16x8*)(pw + ((l15 * 128 + pc) ^ swz));
      bf16x8 pb1 = *(const bf16x8*)(pw + (((16 + l15) * 128 + pc) ^ swz));
      O[0][0] = __builtin_amdgcn_mfma_f32_16x16x32_bf16(va0, pb0, O[0][0], 0, 0, 0);
      O[0][1] = __builtin_amdgcn_mfma_f32_16x16x32_bf16(va0, pb1, O[0][1], 0, 0, 0);
      O[1][0] = __builtin_amdgcn_mfma_f32_16x16x32_bf16(va1, pb0, O[1][0], 0, 0, 0);
      O[1][1] = __builtin_amdgcn_mfma_f32_16x16x32_bf16(va1, pb1, O[1][1], 0, 0, 0);
      O2[0] = __builtin_amdgcn_mfma_f32_16x16x32_bf16(ones, pb0, O2[0], 0, 0, 0);
      O2[1] = __builtin_amdgcn_mfma_f32_16x16x32_bf16(ones, pb1, O2[1], 0, 0, 0);
    }
  }
  // epilogue: denominator is in every lane of O2 (no shuffles needed)
#pragma unroll
  for (int nt = 0; nt < 2; nt++) {
    float inv = __builtin_amdgcn_rcpf(O2[nt][0]);
    int q = qbase + nt * 16 + l15;
#pragma unroll
    for (int dm = 0; dm < 2; dm++) {
      bf16x4 o;
#pragma unroll
      for (int r = 0; r < 4; r++) o[r] = (bf16)(O[dm][nt][r] * inv);
      *(bf16x4*)(att + ((size_t)win * 512 + q) * 128 + head * 32 + dm * 16 +
                 quad * 4) = o;
    }
  }
}

// ---------------------------------------------------------------------------
extern "C" void kernel_launch(void* const* d_in, const int* in_sizes, int n_in,
                              void* d_out, int out_size, void* d_ws,
                              size_t ws_size, hipStream_t stream) {
  const int* rel_index = (const int*)d_in[2];
  char* w = (char*)d_ws;

  int* flag = (int*)w;
  bf16* rb_c = (bf16*)(w + (64ull << 10));
  bf16* qw_c = (bf16*)(w + (128ull << 10));
  bf16* pw_c = (bf16*)(w + (256ull << 10));
  bf16* w1_c = (bf16*)(w + (320ull << 10));
  bf16* w2_c = (bf16*)(w + (512ull << 10));
  bf16* qb_c = (bf16*)(w + (704ull << 10));
  bf16* pb_c = (bf16*)(w + (708ull << 10));
  bf16* g1_c = (bf16*)(w + (712ull << 10));
  bf16* b1n_c = (bf16*)(w + (716ull << 10));
  bf16* g2_c = (bf16*)(w + (720ull << 10));
  bf16* b2n_c = (bf16*)(w + (724ull << 10));
  bf16* mb1_c = (bf16*)(w + (728ull << 10));
  bf16* mb2_c = (bf16*)(w + (732ull << 10));
  bf16* x_c = (bf16*)(w + (1ull << 20));    // [1,17) MB
  bf16* xw = (bf16*)(w + (17ull << 20));    // [17,33) MB; reused: att, h2
  bf16* qkvb = (bf16*)(w + (33ull << 20));  // [33,97) MB; reused: a1
  bf16* x2 = (bf16*)(w + (99ull << 20));    // [99,115) MB; rpem lives here
  bf16* rpem = x2;  // 16 MiB fused rpe+mask planes; dead before proj writes x2
  bf16* att = xw;
  bf16* h2 = xw;
  bf16* a1 = qkvb;

  sniff_k<<<1, 64, 0, stream>>>((const unsigned*)d_in[0], flag);
  canon_big_k<<<4096, 256, 0, stream>>>(d_in[0], x_c, flag);

  CanonArgs ca;
  const int srcidx[13] = {3, 4, 5, 6, 7, 8, 9, 10, 11, 12, 13, 14, 15};
  bf16* dsts[13] = {rb_c, qw_c, qb_c, pw_c, pb_c, g1_c, b1n_c,
                    g2_c, b2n_c, w1_c, mb1_c, w2_c, mb2_c};
  for (int i = 0; i < 13; i++) {
    ca.src[i] = d_in[srcidx[i]];
    ca.dst[i] = dsts[i];
    ca.n[i] = in_sizes[srcidx[i]];
  }
  canon_small_k<<<dim3(256, 13), 256, 0, stream>>>(ca, flag);

  rpem_k<<<8192, 256, 0, stream>>>(rel_index, rb_c, rpem);
  ln_k<1><<<16384, 256, 0, stream>>>(x_c, g1_c, b1n_c, xw);
  gemm_k<0, 128, 384, 128><<<dim3(512, 3), 256, 0, stream>>>(xw, qw_c, qb_c,
                                                             qkvb, nullptr, flag);
  attn_k<<<1024, 512, 0, stream>>>(qkvb, rpem, att);
  gemm_k<1, 64, 128, 128><<<dim3(1024, 1), 256, 0, stream>>>(att, pw_c, pb_c,
                                                             x2, x_c, flag);
  ln_k<0><<<16384, 256, 0, stream>>>(x2, g2_c, b2n_c, h2);
  gemm_k<2, 128, 512, 128><<<dim3(512, 4), 256, 0, stream>>>(h2, w1_c, mb1_c,
                                                             a1, nullptr, flag);
  gemm_k<3, 64, 128, 512><<<dim3(1024, 1), 256, 0, stream>>>(a1, w2_c, mb2_c,
                                                             d_out, x2, flag);
}

// Round 4
// 422.093 us; speedup vs baseline: 1.0936x; 1.0366x over previous
//
#include <hip/hip_runtime.h>
#include <math.h>

typedef __bf16 bf16;
typedef __bf16 bf16x4 __attribute__((ext_vector_type(4)));
typedef __bf16 bf16x8 __attribute__((ext_vector_type(8)));
typedef float f32x4 __attribute__((ext_vector_type(4)));
typedef unsigned short u16;
typedef u16 u16x2 __attribute__((ext_vector_type(2)));

#define LOG2E 1.4426950408889634f

__device__ __forceinline__ float b2f(u16 b) {
  return (float)__builtin_bit_cast(bf16, b);
}

// ---------------------------------------------------------------------------
// dtype sniff (wave-parallel): packed-bf16 words have bits14..7 = bf16
// exponent (~[118,130]); f32 words have uniform mantissa bits there.
// ---------------------------------------------------------------------------
__global__ void sniff_k(const unsigned* __restrict__ xw_, int* __restrict__ flag) {
  int lane = threadIdx.x;  // 64 threads
  int c = 0;
#pragma unroll
  for (int j = 0; j < 4; j++) {
    unsigned e = (xw_[lane * 4 + j] >> 7) & 0xFFu;
    c += (e >= 100u && e <= 140u) ? 1 : 0;
  }
#pragma unroll
  for (int d = 1; d < 64; d <<= 1) c += __shfl_xor(c, d);
  if (lane == 0) *flag = (c >= 150) ? 1 : 0;
}

__global__ __launch_bounds__(256) void canon_big_k(const void* __restrict__ src,
                                                   bf16* __restrict__ dst,
                                                   const int* __restrict__ flag) {
  int i = (blockIdx.x * 256 + threadIdx.x) * 8;
  if (*flag) {
    *(bf16x8*)&dst[i] = *(const bf16x8*)((const bf16*)src + i);
  } else {
    const float* s = (const float*)src + i;
    bf16x8 v;
#pragma unroll
    for (int j = 0; j < 8; j++) v[j] = (bf16)s[j];
    *(bf16x8*)&dst[i] = v;
  }
}

struct CanonArgs {
  const void* src[13];
  bf16* dst[13];
  int n[13];
};

__global__ __launch_bounds__(256) void canon_small_k(CanonArgs a,
                                                     const int* __restrict__ flag) {
  int ti = blockIdx.y;
  int i = blockIdx.x * 256 + threadIdx.x;
  if (i >= a.n[ti]) return;
  if (*flag)
    a.dst[ti][i] = ((const bf16*)a.src[ti])[i];
  else
    a.dst[ti][i] = (bf16)((const float*)a.src[ti])[i];
}

// ---------------------------------------------------------------------------
// Fused rpe+mask planes, exp2-domain:
// rpem[type][h][q][m] = rel_bias[rel_index[q*512+m]][h]*log2e + (masked?-100*log2e:0)
// type bits: 4=d-boundary window (wd==1), 2=h-boundary (wh==7), 1=w-boundary.
// ---------------------------------------------------------------------------
__global__ __launch_bounds__(256) void rpem_k(const int* __restrict__ ridx,
                                              const bf16* __restrict__ rbias,
                                              bf16* __restrict__ rpem) {
  int t = blockIdx.x * 256 + threadIdx.x;  // 2^21 threads, 4 m-values each
  int m0 = (t & 127) * 4, q = (t >> 7) & 511, h = (t >> 16) & 3, ty = t >> 18;
  int qd = q >> 6, qh = (q >> 3) & 7, qw = q & 7;
  int4 ri = *(const int4*)&ridx[q * 512 + m0];
  const int rv[4] = {ri.x, ri.y, ri.z, ri.w};
  bf16x4 o;
#pragma unroll
  for (int j = 0; j < 4; j++) {
    int m = m0 + j;
    int md = m >> 6, mh = (m >> 3) & 7, mw = m & 7;
    bool diff = ((ty & 4) && ((qd < 4) != (md < 4))) ||
                ((ty & 2) && ((qh < 4) != (mh < 4))) ||
                ((ty & 1) && ((qw < 4) != (mw < 4)));
    float v = (float)rbias[rv[j] * 4 + h] * LOG2E;
    o[j] = (bf16)(v + (diff ? -144.2695041f : 0.f));
  }
  *(bf16x4*)&rpem[(size_t)t * 4] = o;
}

// ---------------------------------------------------------------------------
// LayerNorm. ROLL=1: read x at roll(-4)+window-partition source, write window
// layout. ROLL=0: linear in/out. One wave per token (C=128), packed u32 I/O.
// ---------------------------------------------------------------------------
template <int ROLL>
__global__ __launch_bounds__(256) void ln_k(const bf16* __restrict__ x,
                                            const bf16* __restrict__ g,
                                            const bf16* __restrict__ bsh,
                                            bf16* __restrict__ out) {
  int wave = threadIdx.x >> 6, lane = threadIdx.x & 63;
  int tok = blockIdx.x * 4 + wave;
  size_t src;
  if (ROLL) {
    int win = tok >> 9, pos = tok & 511;
    int rd = (win >> 6) * 8 + (pos >> 6);
    int rh = ((win >> 3) & 7) * 8 + ((pos >> 3) & 7);
    int rw = (win & 7) * 8 + (pos & 7);
    int od = (rd + 4) & 15, oh = (rh + 4) & 63, ow = (rw + 4) & 63;
    src = (size_t)((od * 64 + oh) * 64 + ow) * 128;
  } else {
    src = (size_t)tok * 128;
  }
  int ch = lane * 2;
  u16x2 xv = *(const u16x2*)(x + src + ch);
  float f0 = b2f(xv[0]), f1 = b2f(xv[1]);
  float s = f0 + f1, sq = f0 * f0 + f1 * f1;
#pragma unroll
  for (int d = 1; d < 64; d <<= 1) {
    s += __shfl_xor(s, d);
    sq += __shfl_xor(sq, d);
  }
  float mean = s * (1.f / 128.f);
  float var = sq * (1.f / 128.f) - mean * mean;
  float rstd = rsqrtf(fmaxf(var, 0.f) + 1e-5f);
  u16x2 gv = *(const u16x2*)(g + ch), bv = *(const u16x2*)(bsh + ch);
  u16x2 ov;
  ov[0] = __builtin_bit_cast(u16, (bf16)((f0 - mean) * rstd * b2f(gv[0]) + b2f(bv[0])));
  ov[1] = __builtin_bit_cast(u16, (bf16)((f1 - mean) * rstd * b2f(gv[1]) + b2f(bv[1])));
  *(u16x2*)(out + (size_t)tok * 128 + ch) = ov;
}

// ---------------------------------------------------------------------------
// bf16 MFMA GEMM: C[M,N] = A[M,K] @ B[N,K]^T + bias[N] (+ epilogue)
// BM in {128,64}, BN=128, BK=64. A-tile register double-buffer across
// K-chunks. VGPR->ds_write staging. Direct-store epilogue (R1 structure —
// R3's LDS-staged epilogue measured 28 us SLOWER; reverted).
// EPI: 0 = qkv (q scale*log2e, head-major scatter), 1 = proj (win-rev+roll+
//      resid), 2 = mlp1 (tanh-gelu, exp2-based), 3 = mlp2 (resid; flagged out)
// ---------------------------------------------------------------------------
template <int EPI, int BM, int N_, int K_>
__global__ __launch_bounds__(256) void gemm_k(const bf16* __restrict__ A,
                                              const bf16* __restrict__ B,
                                              const bf16* __restrict__ bias,
                                              void* __restrict__ outv,
                                              const bf16* __restrict__ resid,
                                              const int* __restrict__ flag) {
  __shared__ __align__(16) u16 As[BM * 72];
  __shared__ __align__(16) u16 Bs[128 * 72];
  const int t = threadIdx.x;
  const int wave = t >> 6, lane = t & 63, l15 = lane & 15, quad = lane >> 4;
  const int m0 = blockIdx.x * BM, n0 = blockIdx.y * 128;
  constexpr int MI = BM / 32;       // m-frags per wave
  constexpr int PA = BM / 32;       // A staging passes
  int fl = 0;
  if constexpr (EPI == 3) fl = *flag;
  f32x4 acc[MI][4] = {};
  const int wr = (wave >> 1) * (BM / 2), wc = (wave & 1) * 64;
  const int srow = t >> 3, scol = (t & 7) * 8;  // 32 rows per 256-thread pass
  constexpr int NC = K_ / 64;
  bf16x8 avA[PA], avB[PA];
#pragma unroll
  for (int p = 0; p < PA; p++) {
    int row = p * 32 + srow;
    avA[p] = *(const bf16x8*)(A + (size_t)(m0 + row) * K_ + scol);
  }
#pragma unroll
  for (int c = 0; c < NC; c++) {
    const bf16x8* av = (c & 1) ? avB : avA;
    bf16x8* avN = (c & 1) ? avA : avB;
    if (c + 1 < NC) {  // prefetch next A chunk (overlaps this chunk's compute)
#pragma unroll
      for (int p = 0; p < PA; p++) {
        int row = p * 32 + srow;
        avN[p] = *(const bf16x8*)(A + (size_t)(m0 + row) * K_ + (c + 1) * 64 + scol);
      }
    }
    bf16x8 bv[4];
#pragma unroll
    for (int p = 0; p < 4; p++) {
      int row = p * 32 + srow;
      bv[p] = *(const bf16x8*)(B + (size_t)(n0 + row) * K_ + c * 64 + scol);
    }
    __syncthreads();  // prev iter's LDS reads done
#pragma unroll
    for (int p = 0; p < PA; p++)
      *(bf16x8*)&As[(p * 32 + srow) * 72 + scol] = av[p];
#pragma unroll
    for (int p = 0; p < 4; p++)
      *(bf16x8*)&Bs[(p * 32 + srow) * 72 + scol] = bv[p];
    __syncthreads();
#pragma unroll
    for (int ks = 0; ks < 2; ks++) {
      bf16x8 a[MI], b[4];
#pragma unroll
      for (int i = 0; i < MI; i++)
        a[i] = *(const bf16x8*)&As[(wr + i * 16 + l15) * 72 + ks * 32 + quad * 8];
#pragma unroll
      for (int j = 0; j < 4; j++)
        b[j] = *(const bf16x8*)&Bs[(wc + j * 16 + l15) * 72 + ks * 32 + quad * 8];
#pragma unroll
      for (int i = 0; i < MI; i++)
#pragma unroll
        for (int j = 0; j < 4; j++)
          acc[i][j] =
              __builtin_amdgcn_mfma_f32_16x16x32_bf16(a[i], b[j], acc[i][j], 0, 0, 0);
    }
  }
  // q scale folded with log2e for exp2-domain softmax downstream
  const float qscale = 0.17677669529663687f * LOG2E;
#pragma unroll
  for (int i = 0; i < MI; i++) {
#pragma unroll
    for (int r = 0; r < 4; r++) {
      int tok = m0 + wr + i * 16 + quad * 4 + r;
      size_t obase = 0;
      if constexpr (EPI == 1) {
        int win = tok >> 9, pos = tok & 511;
        int rd = (win >> 6) * 8 + (pos >> 6);
        int rh = ((win >> 3) & 7) * 8 + ((pos >> 3) & 7);
        int rw = (win & 7) * 8 + (pos & 7);
        int od = (rd + 4) & 15, oh = (rh + 4) & 63, ow = (rw + 4) & 63;
        obase = (size_t)((od * 64 + oh) * 64 + ow) * 128;
      } else if constexpr (EPI != 0) {
        obase = (size_t)tok * N_;
      }
#pragma unroll
      for (int j = 0; j < 4; j++) {
        int gn = n0 + wc + j * 16 + l15;
        float v = acc[i][j][r] + (float)bias[gn];
        if constexpr (EPI == 0) {
          int tensor = gn >> 7, c = gn & 127, head = c >> 5, d = c & 31;
          if (tensor == 0) v *= qscale;
          int win = tok >> 9, pos = tok & 511;
          size_t off = ((((size_t)tensor * 4 + head) * 128 + win) * 512 + pos) * 32 + d;
          ((bf16*)outv)[off] = (bf16)v;
        } else if constexpr (EPI == 1) {
          v += (float)resid[obase + gn];
          ((bf16*)outv)[obase + gn] = (bf16)v;
        } else if constexpr (EPI == 2) {
          // tanh-GELU via native exp2: g = v - v/(exp2(u2)+1)
          float v2 = v * v;
          float u2 = v * (2.30220806f + 0.10294323f * v2);
          float e2 = exp2f(u2);
          float rcp = __builtin_amdgcn_rcpf(e2 + 1.f);
          v = v - v * rcp;
          ((bf16*)outv)[obase + gn] = (bf16)v;
        } else {
          v += (float)resid[obase + gn];
          if (fl)
            ((bf16*)outv)[obase + gn] = (bf16)v;
          else
            ((float*)outv)[obase + gn] = v;
        }
      }
    }
  }
}

// ---------------------------------------------------------------------------
// Fused window attention, S^T formulation, exp2-domain, BARRIER-FREE K-loop.
// R10: 8-wave shared-V (64 KB LDS, 2 blocks/CU, 16 waves/CU), denominator on
// the MFMA pipe (ones-frag), XOR-swizzled pad-free LDS. Ping-pong 1-tile
// K/rpe register prefetch, 2 tiles per #pragma unroll 1 iteration (bounded
// pressure: ~110 VGPR < 128 cap — R2 spilled via full unroll, R3 stalled
// with no prefetch; this is the middle).
// ---------------------------------------------------------------------------
__global__ __launch_bounds__(512, 4) void attn_k(const bf16* __restrict__ qkv,
                                                 const bf16* __restrict__ rpem,
                                                 bf16* __restrict__ att) {
  __shared__ __align__(16) bf16 sVt[32 * 512];   // V^T [d][key], swizzled, 32 KB
  __shared__ __align__(16) bf16 sP[8][32 * 64];  // per-wave P^T, swizzled, 32 KB
  const int t = threadIdx.x;
  const int p = blockIdx.x;  // [win_hi:4][head:2][qh:1][win_lo:3]
  const int win = ((p >> 6) << 3) | (p & 7);
  const int mid = (p >> 3) & 7;
  const int head = mid >> 1, qh = mid & 1;
  const int wave = t >> 6, lane = t & 63, l15 = lane & 15, quad = lane >> 4;

  const int wd = win >> 6, wh = (win >> 3) & 7, ww = win & 7;
  const int type = ((wd == 1) << 2) | ((wh == 7) << 1) | (ww == 7);

  const size_t hw32 = (size_t)512 * 32;
  const bf16* qp = qkv + ((size_t)(0 * 4 + head) * 128 + win) * hw32;
  const bf16* kp = qkv + ((size_t)(1 * 4 + head) * 128 + win) * hw32;
  const bf16* vp = qkv + ((size_t)(2 * 4 + head) * 128 + win) * hw32;
  const bf16* rpeh = rpem + (size_t)(type * 4 + head) * 512 * 512;
  const int qbase = qh * 256 + wave * 32;

  {  // stage full V^T once (512 threads), XOR-swizzled u32 writes
    int kpi = t >> 3, dblk = (t & 7) * 4;
    char* sb = (char*)sVt;
#pragma unroll
    for (int kb = 0; kb < 4; kb++) {
      const bf16* v0 = vp + (size_t)(kb * 128 + 2 * kpi) * 32 + dblk;
      bf16x4 a = *(const bf16x4*)v0;
      bf16x4 b = *(const bf16x4*)(v0 + 32);
      int keyw = kb * 64 + kpi;
#pragma unroll
      for (int dd = 0; dd < 4; dd++) {
        int row = dblk + dd;
        unsigned wv = (unsigned)__builtin_bit_cast(u16, a[dd]) |
                      ((unsigned)__builtin_bit_cast(u16, b[dd]) << 16);
        *(unsigned*)(sb + ((row * 1024 + keyw * 4) ^ ((row & 7) << 4))) = wv;
      }
    }
  }

  // Q fragments (B operand): lane n=l15 -> query, k=quad*8+j -> d
  bf16x8 qa[2];
#pragma unroll
  for (int nt = 0; nt < 2; nt++)
    qa[nt] = *(const bf16x8*)(qp + (size_t)(qbase + nt * 16 + l15) * 32 + quad * 8);

  // all-ones A-frag for the denominator MFMA
  bf16x8 ones;
#pragma unroll
  for (int e = 0; e < 8; e++) ones[e] = (bf16)1.0f;

  __syncthreads();  // the ONLY block-wide barrier

  f32x4 O[2][2] = {};  // O^T tiles [dm][nt]
  f32x4 O2[2] = {};    // denominator tiles (all rows identical)
  char* pw = (char*)sP[wave];
  const char* sv = (const char*)sVt;
  const int swz = (l15 & 7) << 4;  // row-XOR (same for row and row+16)

  auto load_tile = [&](int kt, bf16x8 (&kbv)[4], bf16x4 (&rvv)[4][2]) {
#pragma unroll
    for (int mt = 0; mt < 4; mt++) {
      kbv[mt] = *(const bf16x8*)(kp + (size_t)(kt * 64 + mt * 16 + l15) * 32 +
                                 quad * 8);
#pragma unroll
      for (int nt = 0; nt < 2; nt++)
        rvv[mt][nt] =
            *(const bf16x4*)(rpeh + (size_t)(qbase + nt * 16 + l15) * 512 +
                             kt * 64 + mt * 16 + quad * 4);
    }
  };

  auto compute_tile = [&](int kt, bf16x8 (&kbv)[4], bf16x4 (&rvv)[4][2]) {
    // S^T = K·Q^T with C initialized to fused rpe+mask (pure load)
    f32x4 S[4][2];
#pragma unroll
    for (int mt = 0; mt < 4; mt++)
#pragma unroll
      for (int nt = 0; nt < 2; nt++) {
        f32x4 c;
#pragma unroll
        for (int r = 0; r < 4; r++) c[r] = (float)rvv[mt][nt][r];
        S[mt][nt] =
            __builtin_amdgcn_mfma_f32_16x16x32_bf16(kbv[mt], qa[nt], c, 0, 0, 0);
      }
    // exp2 + P store (swizzled b64 writes); denominator via MFMA later
#pragma unroll
    for (int nt = 0; nt < 2; nt++)
#pragma unroll
      for (int mt = 0; mt < 4; mt++) {
        bf16x4 pv;
#pragma unroll
        for (int r = 0; r < 4; r++) pv[r] = (bf16)exp2f(S[mt][nt][r]);
        *(bf16x4*)(pw + (((nt * 16 + l15) * 128 + mt * 32 + quad * 8) ^ swz)) = pv;
      }
    // O^T += V^T · P ; denominator += ones · P  (sVt read-only; pw per-wave)
#pragma unroll
    for (int s = 0; s < 2; s++) {
      int vc = kt * 128 + s * 64 + quad * 16;  // byte col into V^T row
      int pc = s * 64 + quad * 16;             // byte col into P row
      bf16x8 va0 = *(const bf16x8*)(sv + ((l15 * 1024 + vc) ^ swz));
      bf16x8 va1 = *(const bf16x8*)(sv + (((16 + l15) * 1024 + vc) ^ swz));
      bf16x8 pb0 = *(const bf16x8*)(pw + ((l15 * 128 + pc) ^ swz));
      bf16x8 pb1 = *(const bf16x8*)(pw + (((16 + l15) * 128 + pc) ^ swz));
      O[0][0] = __builtin_amdgcn_mfma_f32_16x16x32_bf16(va0, pb0, O[0][0], 0, 0, 0);
      O[0][1] = __builtin_amdgcn_mfma_f32_16x16x32_bf16(va0, pb1, O[0][1], 0, 0, 0);
      O[1][0] = __builtin_amdgcn_mfma_f32_16x16x32_bf16(va1, pb0, O[1][0], 0, 0, 0);
      O[1][1] = __builtin_amdgcn_mfma_f32_16x16x32_bf16(va1, pb1, O[1][1], 0, 0, 0);
      O2[0] = __builtin_amdgcn_mfma_f32_16x16x32_bf16(ones, pb0, O2[0], 0, 0, 0);
      O2[1] = __builtin_amdgcn_mfma_f32_16x16x32_bf16(ones, pb1, O2[1], 0, 0, 0);
    }
  };

  bf16x8 kbA[4], kbB[4];
  bf16x4 rvA[4][2], rvB[4][2];
  load_tile(0, kbA, rvA);
#pragma unroll 1
  for (int i = 0; i < 4; i++) {
    int kt = 2 * i;
    load_tile(kt + 1, kbB, rvB);       // prefetch odd tile
    compute_tile(kt, kbA, rvA);        // compute even tile
    if (kt + 2 < 8) load_tile(kt + 2, kbA, rvA);  // prefetch next even
    compute_tile(kt + 1, kbB, rvB);    // compute odd tile
  }
  // epilogue: denominator is in every lane of O2 (no shuffles needed)
#pragma unroll
  for (int nt = 0; nt < 2; nt++) {
    float inv = __builtin_amdgcn_rcpf(O2[nt][0]);
    int q = qbase + nt * 16 + l15;
#pragma unroll
    for (int dm = 0; dm < 2; dm++) {
      bf16x4 o;
#pragma unroll
      for (int r = 0; r < 4; r++) o[r] = (bf16)(O[dm][nt][r] * inv);
      *(bf16x4*)(att + ((size_t)win * 512 + q) * 128 + head * 32 + dm * 16 +
                 quad * 4) = o;
    }
  }
}

// ---------------------------------------------------------------------------
extern "C" void kernel_launch(void* const* d_in, const int* in_sizes, int n_in,
                              void* d_out, int out_size, void* d_ws,
                              size_t ws_size, hipStream_t stream) {
  const int* rel_index = (const int*)d_in[2];
  char* w = (char*)d_ws;

  int* flag = (int*)w;
  bf16* rb_c = (bf16*)(w + (64ull << 10));
  bf16* qw_c = (bf16*)(w + (128ull << 10));
  bf16* pw_c = (bf16*)(w + (256ull << 10));
  bf16* w1_c = (bf16*)(w + (320ull << 10));
  bf16* w2_c = (bf16*)(w + (512ull << 10));
  bf16* qb_c = (bf16*)(w + (704ull << 10));
  bf16* pb_c = (bf16*)(w + (708ull << 10));
  bf16* g1_c = (bf16*)(w + (712ull << 10));
  bf16* b1n_c = (bf16*)(w + (716ull << 10));
  bf16* g2_c = (bf16*)(w + (720ull << 10));
  bf16* b2n_c = (bf16*)(w + (724ull << 10));
  bf16* mb1_c = (bf16*)(w + (728ull << 10));
  bf16* mb2_c = (bf16*)(w + (732ull << 10));
  bf16* x_c = (bf16*)(w + (1ull << 20));    // [1,17) MB
  bf16* xw = (bf16*)(w + (17ull << 20));    // [17,33) MB; reused: att, h2
  bf16* qkvb = (bf16*)(w + (33ull << 20));  // [33,97) MB; reused: a1
  bf16* x2 = (bf16*)(w + (99ull << 20));    // [99,115) MB; rpem lives here
  bf16* rpem = x2;  // 16 MiB fused rpe+mask planes; dead before proj writes x2
  bf16* att = xw;
  bf16* h2 = xw;
  bf16* a1 = qkvb;

  sniff_k<<<1, 64, 0, stream>>>((const unsigned*)d_in[0], flag);
  canon_big_k<<<4096, 256, 0, stream>>>(d_in[0], x_c, flag);

  CanonArgs ca;
  const int srcidx[13] = {3, 4, 5, 6, 7, 8, 9, 10, 11, 12, 13, 14, 15};
  bf16* dsts[13] = {rb_c, qw_c, qb_c, pw_c, pb_c, g1_c, b1n_c,
                    g2_c, b2n_c, w1_c, mb1_c, w2_c, mb2_c};
  for (int i = 0; i < 13; i++) {
    ca.src[i] = d_in[srcidx[i]];
    ca.dst[i] = dsts[i];
    ca.n[i] = in_sizes[srcidx[i]];
  }
  canon_small_k<<<dim3(256, 13), 256, 0, stream>>>(ca, flag);

  rpem_k<<<8192, 256, 0, stream>>>(rel_index, rb_c, rpem);
  ln_k<1><<<16384, 256, 0, stream>>>(x_c, g1_c, b1n_c, xw);
  gemm_k<0, 128, 384, 128><<<dim3(512, 3), 256, 0, stream>>>(xw, qw_c, qb_c,
                                                             qkvb, nullptr, flag);
  attn_k<<<1024, 512, 0, stream>>>(qkvb, rpem, att);
  gemm_k<1, 64, 128, 128><<<dim3(1024, 1), 256, 0, stream>>>(att, pw_c, pb_c,
                                                             x2, x_c, flag);
  ln_k<0><<<16384, 256, 0, stream>>>(x2, g2_c, b2n_c, h2);
  gemm_k<2, 128, 512, 128><<<dim3(512, 4), 256, 0, stream>>>(h2, w1_c, mb1_c,
                                                             a1, nullptr, flag);
  gemm_k<3, 64, 128, 512><<<dim3(1024, 1), 256, 0, stream>>>(a1, w2_c, mb2_c,
                                                             d_out, x2, flag);
}

// Round 5
// 414.629 us; speedup vs baseline: 1.1133x; 1.0180x over previous
//
#include <hip/hip_runtime.h>
#include <math.h>

typedef __bf16 bf16;
typedef __bf16 bf16x4 __attribute__((ext_vector_type(4)));
typedef __bf16 bf16x8 __attribute__((ext_vector_type(8)));
typedef float f32x4 __attribute__((ext_vector_type(4)));
typedef unsigned short u16;
typedef u16 u16x2 __attribute__((ext_vector_type(2)));

#define LOG2E 1.4426950408889634f

__device__ __forceinline__ float b2f(u16 b) {
  return (float)__builtin_bit_cast(bf16, b);
}

// ---------------------------------------------------------------------------
// dtype sniff (wave-parallel): packed-bf16 words have bits14..7 = bf16
// exponent (~[118,130]); f32 words have uniform mantissa bits there.
// ---------------------------------------------------------------------------
__global__ void sniff_k(const unsigned* __restrict__ xw_, int* __restrict__ flag) {
  int lane = threadIdx.x;  // 64 threads
  int c = 0;
#pragma unroll
  for (int j = 0; j < 4; j++) {
    unsigned e = (xw_[lane * 4 + j] >> 7) & 0xFFu;
    c += (e >= 100u && e <= 140u) ? 1 : 0;
  }
#pragma unroll
  for (int d = 1; d < 64; d <<= 1) c += __shfl_xor(c, d);
  if (lane == 0) *flag = (c >= 150) ? 1 : 0;
}

__global__ __launch_bounds__(256) void canon_big_k(const void* __restrict__ src,
                                                   bf16* __restrict__ dst,
                                                   const int* __restrict__ flag) {
  int i = (blockIdx.x * 256 + threadIdx.x) * 8;
  if (*flag) {
    *(bf16x8*)&dst[i] = *(const bf16x8*)((const bf16*)src + i);
  } else {
    const float* s = (const float*)src + i;
    bf16x8 v;
#pragma unroll
    for (int j = 0; j < 8; j++) v[j] = (bf16)s[j];
    *(bf16x8*)&dst[i] = v;
  }
}

struct CanonArgs {
  const void* src[13];
  bf16* dst[13];
  int n[13];
};

__global__ __launch_bounds__(256) void canon_small_k(CanonArgs a,
                                                     const int* __restrict__ flag) {
  int ti = blockIdx.y;
  int i = blockIdx.x * 256 + threadIdx.x;
  if (i >= a.n[ti]) return;
  if (*flag)
    a.dst[ti][i] = ((const bf16*)a.src[ti])[i];
  else
    a.dst[ti][i] = (bf16)((const float*)a.src[ti])[i];
}

// ---------------------------------------------------------------------------
// Fused rpe+mask planes, exp2-domain:
// rpem[type][h][q][m] = rel_bias[rel_index[q*512+m]][h]*log2e + (masked?-100*log2e:0)
// type bits: 4=d-boundary window (wd==1), 2=h-boundary (wh==7), 1=w-boundary.
// ---------------------------------------------------------------------------
__global__ __launch_bounds__(256) void rpem_k(const int* __restrict__ ridx,
                                              const bf16* __restrict__ rbias,
                                              bf16* __restrict__ rpem) {
  int t = blockIdx.x * 256 + threadIdx.x;  // 2^21 threads, 4 m-values each
  int m0 = (t & 127) * 4, q = (t >> 7) & 511, h = (t >> 16) & 3, ty = t >> 18;
  int qd = q >> 6, qh = (q >> 3) & 7, qw = q & 7;
  int4 ri = *(const int4*)&ridx[q * 512 + m0];
  const int rv[4] = {ri.x, ri.y, ri.z, ri.w};
  bf16x4 o;
#pragma unroll
  for (int j = 0; j < 4; j++) {
    int m = m0 + j;
    int md = m >> 6, mh = (m >> 3) & 7, mw = m & 7;
    bool diff = ((ty & 4) && ((qd < 4) != (md < 4))) ||
                ((ty & 2) && ((qh < 4) != (mh < 4))) ||
                ((ty & 1) && ((qw < 4) != (mw < 4)));
    float v = (float)rbias[rv[j] * 4 + h] * LOG2E;
    o[j] = (bf16)(v + (diff ? -144.2695041f : 0.f));
  }
  *(bf16x4*)&rpem[(size_t)t * 4] = o;
}

// ---------------------------------------------------------------------------
// LayerNorm. ROLL=1: read x at roll(-4)+window-partition source, write window
// layout. ROLL=0: linear in/out. One wave per token (C=128), packed u32 I/O.
// ---------------------------------------------------------------------------
template <int ROLL>
__global__ __launch_bounds__(256) void ln_k(const bf16* __restrict__ x,
                                            const bf16* __restrict__ g,
                                            const bf16* __restrict__ bsh,
                                            bf16* __restrict__ out) {
  int wave = threadIdx.x >> 6, lane = threadIdx.x & 63;
  int tok = blockIdx.x * 4 + wave;
  size_t src;
  if (ROLL) {
    int win = tok >> 9, pos = tok & 511;
    int rd = (win >> 6) * 8 + (pos >> 6);
    int rh = ((win >> 3) & 7) * 8 + ((pos >> 3) & 7);
    int rw = (win & 7) * 8 + (pos & 7);
    int od = (rd + 4) & 15, oh = (rh + 4) & 63, ow = (rw + 4) & 63;
    src = (size_t)((od * 64 + oh) * 64 + ow) * 128;
  } else {
    src = (size_t)tok * 128;
  }
  int ch = lane * 2;
  u16x2 xv = *(const u16x2*)(x + src + ch);
  float f0 = b2f(xv[0]), f1 = b2f(xv[1]);
  float s = f0 + f1, sq = f0 * f0 + f1 * f1;
#pragma unroll
  for (int d = 1; d < 64; d <<= 1) {
    s += __shfl_xor(s, d);
    sq += __shfl_xor(sq, d);
  }
  float mean = s * (1.f / 128.f);
  float var = sq * (1.f / 128.f) - mean * mean;
  float rstd = rsqrtf(fmaxf(var, 0.f) + 1e-5f);
  u16x2 gv = *(const u16x2*)(g + ch), bv = *(const u16x2*)(bsh + ch);
  u16x2 ov;
  ov[0] = __builtin_bit_cast(u16, (bf16)((f0 - mean) * rstd * b2f(gv[0]) + b2f(bv[0])));
  ov[1] = __builtin_bit_cast(u16, (bf16)((f1 - mean) * rstd * b2f(gv[1]) + b2f(bv[1])));
  *(u16x2*)(out + (size_t)tok * 128 + ch) = ov;
}

// ---------------------------------------------------------------------------
// bf16 MFMA GEMM: C[M,N] = A[M,K] @ B[N,K]^T + bias[N] (+ epilogue)
// R11: verified 2-phase dbuf global_load_lds template (T3 minimum):
//   - A and B staged together per 64-wide K-chunk via
//     __builtin_amdgcn_global_load_lds width=16 (linear LDS dest,
//     inverse-XOR-swizzled GLOBAL source; ds_read applies the same XOR —
//     both-sides swizzle, <=2-way bank conflicts)
//   - stage(c+1) issued BEFORE compute(c); ONE __syncthreads (= vmcnt(0)
//     drain + barrier) per chunk. Barriers halved; staging VALU ~gone;
//     no VGPR staging buffers.
// Direct-store epilogue (R1 structure; R3's LDS-staged epilogue was slower).
// EPI: 0 = qkv (q scale*log2e, head-major scatter), 1 = proj (win-rev+roll+
//      resid), 2 = mlp1 (tanh-gelu, exp2-based), 3 = mlp2 (resid; flagged out)
// ---------------------------------------------------------------------------
template <int EPI, int BM, int N_, int K_>
__global__ __launch_bounds__(256) void gemm_k(const bf16* __restrict__ A,
                                              const bf16* __restrict__ B,
                                              const bf16* __restrict__ bias,
                                              void* __restrict__ outv,
                                              const bf16* __restrict__ resid,
                                              const int* __restrict__ flag) {
  __shared__ __align__(16) u16 SM[2][(BM + 128) * 64];
  const int t = threadIdx.x;
  const int wave = t >> 6, lane = t & 63, l15 = lane & 15, quad = lane >> 4;
  const int m0 = blockIdx.x * BM, n0 = blockIdx.y * 128;
  constexpr int MI = BM / 32;        // m-frags per wave
  constexpr int NC = K_ / 64;        // K chunks
  constexpr int PASSES = (BM + 128) / 32;  // 32 rows staged per 256-thr pass
  int fl = 0;
  if constexpr (EPI == 3) fl = *flag;
  f32x4 acc[MI][4] = {};
  const int wr = (wave >> 1) * (BM / 2), wc = (wave & 1) * 64;
  const int srow = t >> 3;  // staging row within pass
  const int sc16 = t & 7;   // 16B chunk within 128B row

  // stage chunk c into SM[buf]: dest linear (global_load_lds requirement),
  // source column pre-swizzled so that LDS col x holds source col x^(row&7)
  auto stage = [&](int c, int buf) {
#pragma unroll
    for (int p = 0; p < PASSES; p++) {
      int row = p * 32 + srow;
      int cs = sc16 ^ (row & 7);
      const u16* src;
      if (row < BM)
        src = (const u16*)A + (size_t)(m0 + row) * K_ + c * 64 + cs * 8;
      else
        src = (const u16*)B + (size_t)(n0 + row - BM) * K_ + c * 64 + cs * 8;
      __builtin_amdgcn_global_load_lds(
          (const __attribute__((address_space(1))) void*)src,
          (__attribute__((address_space(3))) void*)&SM[buf][row * 64 + sc16 * 8],
          16, 0, 0);
    }
  };

  stage(0, 0);
  __syncthreads();  // vmcnt(0) drain + barrier: buf0 fully staged (all waves)
#pragma unroll
  for (int c = 0; c < NC; c++) {
    if (c + 1 < NC) stage(c + 1, (c + 1) & 1);  // issue early; hides under MFMA
    const char* cur = (const char*)SM[c & 1];
#pragma unroll
    for (int ks = 0; ks < 2; ks++) {
      bf16x8 a[MI], b[4];
#pragma unroll
      for (int i = 0; i < MI; i++) {
        int row = wr + i * 16 + l15;
        a[i] = *(const bf16x8*)(cur + row * 128 +
                                (((ks * 4 + quad) ^ (row & 7)) << 4));
      }
#pragma unroll
      for (int j = 0; j < 4; j++) {
        int row = BM + wc + j * 16 + l15;
        b[j] = *(const bf16x8*)(cur + row * 128 +
                                (((ks * 4 + quad) ^ (row & 7)) << 4));
      }
#pragma unroll
      for (int i = 0; i < MI; i++)
#pragma unroll
        for (int j = 0; j < 4; j++)
          acc[i][j] =
              __builtin_amdgcn_mfma_f32_16x16x32_bf16(a[i], b[j], acc[i][j], 0, 0, 0);
    }
    if (c + 1 < NC) __syncthreads();  // next buf staged; cur reads done
  }
  // q scale folded with log2e for exp2-domain softmax downstream
  const float qscale = 0.17677669529663687f * LOG2E;
#pragma unroll
  for (int i = 0; i < MI; i++) {
#pragma unroll
    for (int r = 0; r < 4; r++) {
      int tok = m0 + wr + i * 16 + quad * 4 + r;
      size_t obase = 0;
      if constexpr (EPI == 1) {
        int win = tok >> 9, pos = tok & 511;
        int rd = (win >> 6) * 8 + (pos >> 6);
        int rh = ((win >> 3) & 7) * 8 + ((pos >> 3) & 7);
        int rw = (win & 7) * 8 + (pos & 7);
        int od = (rd + 4) & 15, oh = (rh + 4) & 63, ow = (rw + 4) & 63;
        obase = (size_t)((od * 64 + oh) * 64 + ow) * 128;
      } else if constexpr (EPI != 0) {
        obase = (size_t)tok * N_;
      }
#pragma unroll
      for (int j = 0; j < 4; j++) {
        int gn = n0 + wc + j * 16 + l15;
        float v = acc[i][j][r] + (float)bias[gn];
        if constexpr (EPI == 0) {
          int tensor = gn >> 7, c = gn & 127, head = c >> 5, d = c & 31;
          if (tensor == 0) v *= qscale;
          int win = tok >> 9, pos = tok & 511;
          size_t off = ((((size_t)tensor * 4 + head) * 128 + win) * 512 + pos) * 32 + d;
          ((bf16*)outv)[off] = (bf16)v;
        } else if constexpr (EPI == 1) {
          v += (float)resid[obase + gn];
          ((bf16*)outv)[obase + gn] = (bf16)v;
        } else if constexpr (EPI == 2) {
          // tanh-GELU via native exp2: g = v - v/(exp2(u2)+1)
          float v2 = v * v;
          float u2 = v * (2.30220806f + 0.10294323f * v2);
          float e2 = exp2f(u2);
          float rcp = __builtin_amdgcn_rcpf(e2 + 1.f);
          v = v - v * rcp;
          ((bf16*)outv)[obase + gn] = (bf16)v;
        } else {
          v += (float)resid[obase + gn];
          if (fl)
            ((bf16*)outv)[obase + gn] = (bf16)v;
          else
            ((float*)outv)[obase + gn] = v;
        }
      }
    }
  }
}

// ---------------------------------------------------------------------------
// Fused window attention, S^T formulation, exp2-domain, BARRIER-FREE K-loop.
// R3-measured structure (85.8 us), verbatim: 8-wave shared-V (64 KB LDS,
// 2 blocks/CU, 16 waves/CU), denominator on the MFMA pipe (ones-frag),
// XOR-swizzled pad-free LDS, #pragma unroll 1 in-loop loads (no prefetch —
// R2 full-unroll and R4 lambda ping-pong both spilled to scratch).
// ---------------------------------------------------------------------------
__global__ __launch_bounds__(512, 4) void attn_k(const bf16* __restrict__ qkv,
                                                 const bf16* __restrict__ rpem,
                                                 bf16* __restrict__ att) {
  __shared__ __align__(16) bf16 sVt[32 * 512];   // V^T [d][key], swizzled, 32 KB
  __shared__ __align__(16) bf16 sP[8][32 * 64];  // per-wave P^T, swizzled, 32 KB
  const int t = threadIdx.x;
  const int p = blockIdx.x;  // [win_hi:4][head:2][qh:1][win_lo:3]
  const int win = ((p >> 6) << 3) | (p & 7);
  const int mid = (p >> 3) & 7;
  const int head = mid >> 1, qh = mid & 1;
  const int wave = t >> 6, lane = t & 63, l15 = lane & 15, quad = lane >> 4;

  const int wd = win >> 6, wh = (win >> 3) & 7, ww = win & 7;
  const int type = ((wd == 1) << 2) | ((wh == 7) << 1) | (ww == 7);

  const size_t hw32 = (size_t)512 * 32;
  const bf16* qp = qkv + ((size_t)(0 * 4 + head) * 128 + win) * hw32;
  const bf16* kp = qkv + ((size_t)(1 * 4 + head) * 128 + win) * hw32;
  const bf16* vp = qkv + ((size_t)(2 * 4 + head) * 128 + win) * hw32;
  const bf16* rpeh = rpem + (size_t)(type * 4 + head) * 512 * 512;
  const int qbase = qh * 256 + wave * 32;

  {  // stage full V^T once (512 threads), XOR-swizzled u32 writes
    int kpi = t >> 3, dblk = (t & 7) * 4;
    char* sb = (char*)sVt;
#pragma unroll
    for (int kb = 0; kb < 4; kb++) {
      const bf16* v0 = vp + (size_t)(kb * 128 + 2 * kpi) * 32 + dblk;
      bf16x4 a = *(const bf16x4*)v0;
      bf16x4 b = *(const bf16x4*)(v0 + 32);
      int keyw = kb * 64 + kpi;
#pragma unroll
      for (int dd = 0; dd < 4; dd++) {
        int row = dblk + dd;
        unsigned wv = (unsigned)__builtin_bit_cast(u16, a[dd]) |
                      ((unsigned)__builtin_bit_cast(u16, b[dd]) << 16);
        *(unsigned*)(sb + ((row * 1024 + keyw * 4) ^ ((row & 7) << 4))) = wv;
      }
    }
  }

  // Q fragments (B operand): lane n=l15 -> query, k=quad*8+j -> d
  bf16x8 qa[2];
#pragma unroll
  for (int nt = 0; nt < 2; nt++)
    qa[nt] = *(const bf16x8*)(qp + (size_t)(qbase + nt * 16 + l15) * 32 + quad * 8);

  // all-ones A-frag for the denominator MFMA
  bf16x8 ones;
#pragma unroll
  for (int e = 0; e < 8; e++) ones[e] = (bf16)1.0f;

  __syncthreads();  // the ONLY block-wide barrier

  f32x4 O[2][2] = {};  // O^T tiles [dm][nt]
  f32x4 O2[2] = {};    // denominator tiles (all rows identical)
  char* pw = (char*)sP[wave];
  const char* sv = (const char*)sVt;
  const int swz = (l15 & 7) << 4;  // row-XOR (same for row and row+16)

#pragma unroll 1
  for (int kt = 0; kt < 8; kt++) {
    // K frags + fused rpe+mask C-init (in-loop loads; 16 waves/CU hide them)
    bf16x8 kb[4];
    bf16x4 rv[4][2];
#pragma unroll
    for (int mt = 0; mt < 4; mt++) {
      kb[mt] = *(const bf16x8*)(kp + (size_t)(kt * 64 + mt * 16 + l15) * 32 +
                                quad * 8);
#pragma unroll
      for (int nt = 0; nt < 2; nt++)
        rv[mt][nt] =
            *(const bf16x4*)(rpeh + (size_t)(qbase + nt * 16 + l15) * 512 +
                             kt * 64 + mt * 16 + quad * 4);
    }
    // S^T = K·Q^T with C initialized to fused rpe+mask (pure load)
    f32x4 S[4][2];
#pragma unroll
    for (int mt = 0; mt < 4; mt++)
#pragma unroll
      for (int nt = 0; nt < 2; nt++) {
        f32x4 c;
#pragma unroll
        for (int r = 0; r < 4; r++) c[r] = (float)rv[mt][nt][r];
        S[mt][nt] = __builtin_amdgcn_mfma_f32_16x16x32_bf16(kb[mt], qa[nt], c, 0, 0, 0);
      }
    // exp2 + P store (swizzled b64 writes); denominator via MFMA
#pragma unroll
    for (int nt = 0; nt < 2; nt++)
#pragma unroll
      for (int mt = 0; mt < 4; mt++) {
        bf16x4 pv;
#pragma unroll
        for (int r = 0; r < 4; r++) pv[r] = (bf16)exp2f(S[mt][nt][r]);
        *(bf16x4*)(pw + (((nt * 16 + l15) * 128 + mt * 32 + quad * 8) ^ swz)) = pv;
      }
    // O^T += V^T · P ; denominator += ones · P  (sVt read-only; pw per-wave)
#pragma unroll
    for (int s = 0; s < 2; s++) {
      int vc = kt * 128 + s * 64 + quad * 16;  // byte col into V^T row
      int pc = s * 64 + quad * 16;             // byte col into P row
      bf16x8 va0 = *(const bf16x8*)(sv + ((l15 * 1024 + vc) ^ swz));
      bf16x8 va1 = *(const bf16x8*)(sv + (((16 + l15) * 1024 + vc) ^ swz));
      bf16x8 pb0 = *(const bf16x8*)(pw + ((l15 * 128 + pc) ^ swz));
      bf16x8 pb1 = *(const bf16x8*)(pw + (((16 + l15) * 128 + pc) ^ swz));
      O[0][0] = __builtin_amdgcn_mfma_f32_16x16x32_bf16(va0, pb0, O[0][0], 0, 0, 0);
      O[0][1] = __builtin_amdgcn_mfma_f32_16x16x32_bf16(va0, pb1, O[0][1], 0, 0, 0);
      O[1][0] = __builtin_amdgcn_mfma_f32_16x16x32_bf16(va1, pb0, O[1][0], 0, 0, 0);
      O[1][1] = __builtin_amdgcn_mfma_f32_16x16x32_bf16(va1, pb1, O[1][1], 0, 0, 0);
      O2[0] = __builtin_amdgcn_mfma_f32_16x16x32_bf16(ones, pb0, O2[0], 0, 0, 0);
      O2[1] = __builtin_amdgcn_mfma_f32_16x16x32_bf16(ones, pb1, O2[1], 0, 0, 0);
    }
  }
  // epilogue: denominator is in every lane of O2 (no shuffles needed)
#pragma unroll
  for (int nt = 0; nt < 2; nt++) {
    float inv = __builtin_amdgcn_rcpf(O2[nt][0]);
    int q = qbase + nt * 16 + l15;
#pragma unroll
    for (int dm = 0; dm < 2; dm++) {
      bf16x4 o;
#pragma unroll
      for (int r = 0; r < 4; r++) o[r] = (bf16)(O[dm][nt][r] * inv);
      *(bf16x4*)(att + ((size_t)win * 512 + q) * 128 + head * 32 + dm * 16 +
                 quad * 4) = o;
    }
  }
}

// ---------------------------------------------------------------------------
extern "C" void kernel_launch(void* const* d_in, const int* in_sizes, int n_in,
                              void* d_out, int out_size, void* d_ws,
                              size_t ws_size, hipStream_t stream) {
  const int* rel_index = (const int*)d_in[2];
  char* w = (char*)d_ws;

  int* flag = (int*)w;
  bf16* rb_c = (bf16*)(w + (64ull << 10));
  bf16* qw_c = (bf16*)(w + (128ull << 10));
  bf16* pw_c = (bf16*)(w + (256ull << 10));
  bf16* w1_c = (bf16*)(w + (320ull << 10));
  bf16* w2_c = (bf16*)(w + (512ull << 10));
  bf16* qb_c = (bf16*)(w + (704ull << 10));
  bf16* pb_c = (bf16*)(w + (708ull << 10));
  bf16* g1_c = (bf16*)(w + (712ull << 10));
  bf16* b1n_c = (bf16*)(w + (716ull << 10));
  bf16* g2_c = (bf16*)(w + (720ull << 10));
  bf16* b2n_c = (bf16*)(w + (724ull << 10));
  bf16* mb1_c = (bf16*)(w + (728ull << 10));
  bf16* mb2_c = (bf16*)(w + (732ull << 10));
  bf16* x_c = (bf16*)(w + (1ull << 20));    // [1,17) MB
  bf16* xw = (bf16*)(w + (17ull << 20));    // [17,33) MB; reused: att, h2
  bf16* qkvb = (bf16*)(w + (33ull << 20));  // [33,97) MB; reused: a1
  bf16* x2 = (bf16*)(w + (99ull << 20));    // [99,115) MB; rpem lives here
  bf16* rpem = x2;  // 16 MiB fused rpe+mask planes; dead before proj writes x2
  bf16* att = xw;
  bf16* h2 = xw;
  bf16* a1 = qkvb;

  sniff_k<<<1, 64, 0, stream>>>((const unsigned*)d_in[0], flag);
  canon_big_k<<<4096, 256, 0, stream>>>(d_in[0], x_c, flag);

  CanonArgs ca;
  const int srcidx[13] = {3, 4, 5, 6, 7, 8, 9, 10, 11, 12, 13, 14, 15};
  bf16* dsts[13] = {rb_c, qw_c, qb_c, pw_c, pb_c, g1_c, b1n_c,
                    g2_c, b2n_c, w1_c, mb1_c, w2_c, mb2_c};
  for (int i = 0; i < 13; i++) {
    ca.src[i] = d_in[srcidx[i]];
    ca.dst[i] = dsts[i];
    ca.n[i] = in_sizes[srcidx[i]];
  }
  canon_small_k<<<dim3(256, 13), 256, 0, stream>>>(ca, flag);

  rpem_k<<<8192, 256, 0, stream>>>(rel_index, rb_c, rpem);
  ln_k<1><<<16384, 256, 0, stream>>>(x_c, g1_c, b1n_c, xw);
  gemm_k<0, 128, 384, 128><<<dim3(512, 3), 256, 0, stream>>>(xw, qw_c, qb_c,
                                                             qkvb, nullptr, flag);
  attn_k<<<1024, 512, 0, stream>>>(qkvb, rpem, att);
  gemm_k<1, 64, 128, 128><<<dim3(1024, 1), 256, 0, stream>>>(att, pw_c, pb_c,
                                                             x2, x_c, flag);
  ln_k<0><<<16384, 256, 0, stream>>>(x2, g2_c, b2n_c, h2);
  gemm_k<2, 128, 512, 128><<<dim3(512, 4), 256, 0, stream>>>(h2, w1_c, mb1_c,
                                                             a1, nullptr, flag);
  gemm_k<3, 64, 128, 512><<<dim3(1024, 1), 256, 0, stream>>>(a1, w2_c, mb2_c,
                                                             d_out, x2, flag);
}

// Round 6
// 390.134 us; speedup vs baseline: 1.1832x; 1.0628x over previous
//
#include <hip/hip_runtime.h>
#include <math.h>

typedef __bf16 bf16;
typedef __bf16 bf16x4 __attribute__((ext_vector_type(4)));
typedef __bf16 bf16x8 __attribute__((ext_vector_type(8)));
typedef float f32x4 __attribute__((ext_vector_type(4)));
typedef unsigned short u16;
typedef u16 u16x2 __attribute__((ext_vector_type(2)));

#define LOG2E 1.4426950408889634f

__device__ __forceinline__ float b2f(u16 b) {
  return (float)__builtin_bit_cast(bf16, b);
}

// ---------------------------------------------------------------------------
// dtype sniff (wave-parallel): packed-bf16 words have bits14..7 = bf16
// exponent (~[118,130]); f32 words have uniform mantissa bits there.
// ---------------------------------------------------------------------------
__global__ void sniff_k(const unsigned* __restrict__ xw_, int* __restrict__ flag) {
  int lane = threadIdx.x;  // 64 threads
  int c = 0;
#pragma unroll
  for (int j = 0; j < 4; j++) {
    unsigned e = (xw_[lane * 4 + j] >> 7) & 0xFFu;
    c += (e >= 100u && e <= 140u) ? 1 : 0;
  }
#pragma unroll
  for (int d = 1; d < 64; d <<= 1) c += __shfl_xor(c, d);
  if (lane == 0) *flag = (c >= 150) ? 1 : 0;
}

struct CanonArgs {
  const void* src[13];
  bf16* dst[13];
  int n[13];
};

__global__ __launch_bounds__(256) void canon_small_k(CanonArgs a,
                                                     const int* __restrict__ flag) {
  int ti = blockIdx.y;
  int i = blockIdx.x * 256 + threadIdx.x;
  if (i >= a.n[ti]) return;
  if (*flag)
    a.dst[ti][i] = ((const bf16*)a.src[ti])[i];
  else
    a.dst[ti][i] = (bf16)((const float*)a.src[ti])[i];
}

// ---------------------------------------------------------------------------
// Fused rpe+mask planes, exp2-domain, PERMUTED to the attn fragment layout:
// plane[type][h] is [kt:8][quad:4][q:512][mt:4][r:4] (512^2 elems), so each
// attn lane reads its 16 C-init values as two contiguous b128s.
// value = rel_bias[rel_index[q*512+m]][h]*log2e + (masked?-100*log2e:0),
// m = kt*64 + mt*16 + quad*4 + r.
// type bits: 4=d-boundary window (wd==1), 2=h-boundary (wh==7), 1=w-boundary.
// ---------------------------------------------------------------------------
__global__ __launch_bounds__(256) void rpem_k(const int* __restrict__ ridx,
                                              const bf16* __restrict__ rbias,
                                              bf16* __restrict__ rpem) {
  int t = blockIdx.x * 256 + threadIdx.x;  // 2^21 threads, 4 m-values each
  int m0 = (t & 127) * 4, q = (t >> 7) & 511, h = (t >> 16) & 3, ty = t >> 18;
  int qd = q >> 6, qh = (q >> 3) & 7, qw = q & 7;
  int kt = m0 >> 6, mt = (m0 >> 4) & 3, quad = (m0 >> 2) & 3;
  int4 ri = *(const int4*)&ridx[q * 512 + m0];
  const int rv[4] = {ri.x, ri.y, ri.z, ri.w};
  bf16x4 o;
#pragma unroll
  for (int j = 0; j < 4; j++) {
    int m = m0 + j;
    int md = m >> 6, mh = (m >> 3) & 7, mw = m & 7;
    bool diff = ((ty & 4) && ((qd < 4) != (md < 4))) ||
                ((ty & 2) && ((qh < 4) != (mh < 4))) ||
                ((ty & 1) && ((qw < 4) != (mw < 4)));
    float v = (float)rbias[rv[j] * 4 + h] * LOG2E;
    o[j] = (bf16)(v + (diff ? -144.2695041f : 0.f));
  }
  size_t out = ((size_t)(ty * 4 + h) << 18) +
               (((size_t)(kt * 4 + quad) * 512 + q) * 16 + mt * 4);
  *(bf16x4*)&rpem[out] = o;
}

// ---------------------------------------------------------------------------
// LayerNorm. ROLL=1: read RAW input (flag: bf16/f32) at roll(-4)+window-
// partition source, write window layout (canon_big fused away). ROLL=0:
// linear bf16 in/out. One wave per token (C=128).
// ---------------------------------------------------------------------------
template <int ROLL>
__global__ __launch_bounds__(256) void ln_k(const void* __restrict__ xin,
                                            const bf16* __restrict__ g,
                                            const bf16* __restrict__ bsh,
                                            bf16* __restrict__ out,
                                            const int* __restrict__ flag) {
  int wave = threadIdx.x >> 6, lane = threadIdx.x & 63;
  int tok = blockIdx.x * 4 + wave;
  size_t src;
  if (ROLL) {
    int win = tok >> 9, pos = tok & 511;
    int rd = (win >> 6) * 8 + (pos >> 6);
    int rh = ((win >> 3) & 7) * 8 + ((pos >> 3) & 7);
    int rw = (win & 7) * 8 + (pos & 7);
    int od = (rd + 4) & 15, oh = (rh + 4) & 63, ow = (rw + 4) & 63;
    src = (size_t)((od * 64 + oh) * 64 + ow) * 128;
  } else {
    src = (size_t)tok * 128;
  }
  int ch = lane * 2;
  float f0, f1;
  if (ROLL && !*flag) {
    const float* xf = (const float*)xin + src + ch;
    f0 = xf[0];
    f1 = xf[1];
  } else {
    u16x2 xv = *(const u16x2*)((const bf16*)xin + src + ch);
    f0 = b2f(xv[0]);
    f1 = b2f(xv[1]);
  }
  float s = f0 + f1, sq = f0 * f0 + f1 * f1;
#pragma unroll
  for (int d = 1; d < 64; d <<= 1) {
    s += __shfl_xor(s, d);
    sq += __shfl_xor(sq, d);
  }
  float mean = s * (1.f / 128.f);
  float var = sq * (1.f / 128.f) - mean * mean;
  float rstd = rsqrtf(fmaxf(var, 0.f) + 1e-5f);
  u16x2 gv = *(const u16x2*)(g + ch), bv = *(const u16x2*)(bsh + ch);
  u16x2 ov;
  ov[0] = __builtin_bit_cast(u16, (bf16)((f0 - mean) * rstd * b2f(gv[0]) + b2f(bv[0])));
  ov[1] = __builtin_bit_cast(u16, (bf16)((f1 - mean) * rstd * b2f(gv[1]) + b2f(bv[1])));
  *(u16x2*)(out + (size_t)tok * 128 + ch) = ov;
}

// ---------------------------------------------------------------------------
// bf16 MFMA GEMM: C[M,N] = A[M,K] @ B[N,K]^T + bias[N] (+ epilogue)
// R12 geometry for tiny-K: BM=64, BK=K for K=128 GEMMs (single stage ->
// one drain barrier total), LDS 48 KB -> 3 blocks/CU = 12 waves/CU (was 2
// blocks, 8 waves: R5 post-mortem = GEMMs latency-bound, not schedule-bound).
// mlp2 (K=512) uses BK=64 double-buffer (NC=8, true 2-phase pipeline).
// global_load_lds width=16, linear LDS dest, inverse-XOR-swizzled global
// source, XOR on ds_read (both-sides swizzle). Direct-store epilogue.
// EPI: 0 = qkv (q scale*log2e, head-major scatter), 1 = proj (win-rev+roll+
//      RAW-resid via flag), 2 = mlp1 (tanh-gelu), 3 = mlp2 (resid; flagged out)
// ---------------------------------------------------------------------------
template <int EPI, int BM, int BK, int N_, int K_>
__global__ __launch_bounds__(256) void gemm_k(const bf16* __restrict__ A,
                                              const bf16* __restrict__ B,
                                              const bf16* __restrict__ bias,
                                              void* __restrict__ outv,
                                              const void* __restrict__ residv,
                                              const int* __restrict__ flag) {
  constexpr int NC = K_ / BK;
  constexpr int NBUF = (NC > 1) ? 2 : 1;
  __shared__ __align__(16) u16 SM[NBUF][(BM + 128) * BK];
  const int t = threadIdx.x;
  const int wave = t >> 6, lane = t & 63, l15 = lane & 15, quad = lane >> 4;
  const int m0 = blockIdx.x * BM, n0 = blockIdx.y * 128;
  constexpr int MI = BM / 32;  // m-frags per wave
  int fl = 0;
  if constexpr (EPI == 1 || EPI == 3) fl = *flag;
  f32x4 acc[MI][4] = {};
  const int wr = (wave >> 1) * (BM / 2), wc = (wave & 1) * 64;
  constexpr int TPR = BK / 8;        // 16B chunks per row
  constexpr int RPP = 256 / TPR;     // rows staged per 256-thread pass
  constexpr int PASSES = (BM + 128) / RPP;
  const int srow = t / TPR, sc16 = t % TPR;

  // stage chunk c into SM[buf]: dest linear (global_load_lds requirement),
  // source chunk pre-swizzled: LDS chunk x of row holds source chunk
  // x^(row&7); reader applies the same XOR.
  auto stage = [&](int c, int buf) {
#pragma unroll
    for (int p = 0; p < PASSES; p++) {
      int row = p * RPP + srow;
      int cs = sc16 ^ (row & 7);
      const u16* src;
      if (row < BM)
        src = (const u16*)A + (size_t)(m0 + row) * K_ + c * BK + cs * 8;
      else
        src = (const u16*)B + (size_t)(n0 + row - BM) * K_ + c * BK + cs * 8;
      __builtin_amdgcn_global_load_lds(
          (const __attribute__((address_space(1))) void*)src,
          (__attribute__((address_space(3))) void*)&SM[buf][row * BK + sc16 * 8],
          16, 0, 0);
    }
  };

  stage(0, 0);
  __syncthreads();  // vmcnt(0) drain + barrier: buf0 fully staged
#pragma unroll
  for (int c = 0; c < NC; c++) {
    if (c + 1 < NC) stage(c + 1, (c + 1) & 1);  // issue early; hides under MFMA
    const char* cur = (const char*)SM[c & 1];
#pragma unroll
    for (int ks = 0; ks < BK / 32; ks++) {
      bf16x8 a[MI], b[4];
#pragma unroll
      for (int i = 0; i < MI; i++) {
        int row = wr + i * 16 + l15;
        a[i] = *(const bf16x8*)(cur + row * (BK * 2) +
                                (((ks * 4 + quad) ^ (row & 7)) << 4));
      }
#pragma unroll
      for (int j = 0; j < 4; j++) {
        int row = BM + wc + j * 16 + l15;
        b[j] = *(const bf16x8*)(cur + row * (BK * 2) +
                                (((ks * 4 + quad) ^ (row & 7)) << 4));
      }
#pragma unroll
      for (int i = 0; i < MI; i++)
#pragma unroll
        for (int j = 0; j < 4; j++)
          acc[i][j] =
              __builtin_amdgcn_mfma_f32_16x16x32_bf16(a[i], b[j], acc[i][j], 0, 0, 0);
    }
    if (c + 1 < NC) __syncthreads();  // next buf staged; cur reads done
  }
  // q scale folded with log2e for exp2-domain softmax downstream
  const float qscale = 0.17677669529663687f * LOG2E;
#pragma unroll
  for (int i = 0; i < MI; i++) {
#pragma unroll
    for (int r = 0; r < 4; r++) {
      int tok = m0 + wr + i * 16 + quad * 4 + r;
      size_t obase = 0;
      if constexpr (EPI == 1) {
        int win = tok >> 9, pos = tok & 511;
        int rd = (win >> 6) * 8 + (pos >> 6);
        int rh = ((win >> 3) & 7) * 8 + ((pos >> 3) & 7);
        int rw = (win & 7) * 8 + (pos & 7);
        int od = (rd + 4) & 15, oh = (rh + 4) & 63, ow = (rw + 4) & 63;
        obase = (size_t)((od * 64 + oh) * 64 + ow) * 128;
      } else if constexpr (EPI != 0) {
        obase = (size_t)tok * N_;
      }
#pragma unroll
      for (int j = 0; j < 4; j++) {
        int gn = n0 + wc + j * 16 + l15;
        float v = acc[i][j][r] + (float)bias[gn];
        if constexpr (EPI == 0) {
          int tensor = gn >> 7, c = gn & 127, head = c >> 5, d = c & 31;
          if (tensor == 0) v *= qscale;
          int win = tok >> 9, pos = tok & 511;
          size_t off = ((((size_t)tensor * 4 + head) * 128 + win) * 512 + pos) * 32 + d;
          ((bf16*)outv)[off] = (bf16)v;
        } else if constexpr (EPI == 1) {
          // resid = RAW input (canon_big fused away): flag-dispatched dtype
          float rs = fl ? (float)((const bf16*)residv)[obase + gn]
                        : ((const float*)residv)[obase + gn];
          v += rs;
          ((bf16*)outv)[obase + gn] = (bf16)v;
        } else if constexpr (EPI == 2) {
          // tanh-GELU via native exp2: g = v - v/(exp2(u2)+1)
          float v2 = v * v;
          float u2 = v * (2.30220806f + 0.10294323f * v2);
          float e2 = exp2f(u2);
          float rcp = __builtin_amdgcn_rcpf(e2 + 1.f);
          v = v - v * rcp;
          ((bf16*)outv)[obase + gn] = (bf16)v;
        } else {
          v += (float)((const bf16*)residv)[obase + gn];
          if (fl)
            ((bf16*)outv)[obase + gn] = (bf16)v;
          else
            ((float*)outv)[obase + gn] = v;
        }
      }
    }
  }
}

// ---------------------------------------------------------------------------
// Fused window attention, S^T formulation, exp2-domain, BARRIER-FREE K-loop.
// R3-measured structure (85.8 us): 8-wave shared-V (64 KB LDS, 2 blocks/CU),
// denominator on the MFMA pipe (ones-frag), XOR-swizzled pad-free LDS,
// #pragma unroll 1 in-loop loads (R2/R4 prefetch attempts both spilled).
// R12: rpem loads use the permuted layout -> 4 coalesced b128/kt (was 8 b64).
// ---------------------------------------------------------------------------
__global__ __launch_bounds__(512, 4) void attn_k(const bf16* __restrict__ qkv,
                                                 const bf16* __restrict__ rpem,
                                                 bf16* __restrict__ att) {
  __shared__ __align__(16) bf16 sVt[32 * 512];   // V^T [d][key], swizzled, 32 KB
  __shared__ __align__(16) bf16 sP[8][32 * 64];  // per-wave P^T, swizzled, 32 KB
  const int t = threadIdx.x;
  const int p = blockIdx.x;  // [win_hi:4][head:2][qh:1][win_lo:3]
  const int win = ((p >> 6) << 3) | (p & 7);
  const int mid = (p >> 3) & 7;
  const int head = mid >> 1, qh = mid & 1;
  const int wave = t >> 6, lane = t & 63, l15 = lane & 15, quad = lane >> 4;

  const int wd = win >> 6, wh = (win >> 3) & 7, ww = win & 7;
  const int type = ((wd == 1) << 2) | ((wh == 7) << 1) | (ww == 7);

  const size_t hw32 = (size_t)512 * 32;
  const bf16* qp = qkv + ((size_t)(0 * 4 + head) * 128 + win) * hw32;
  const bf16* kp = qkv + ((size_t)(1 * 4 + head) * 128 + win) * hw32;
  const bf16* vp = qkv + ((size_t)(2 * 4 + head) * 128 + win) * hw32;
  const bf16* rpeh = rpem + ((size_t)(type * 4 + head) << 18);
  const int qbase = qh * 256 + wave * 32;

  {  // stage full V^T once (512 threads), XOR-swizzled u32 writes
    int kpi = t >> 3, dblk = (t & 7) * 4;
    char* sb = (char*)sVt;
#pragma unroll
    for (int kb = 0; kb < 4; kb++) {
      const bf16* v0 = vp + (size_t)(kb * 128 + 2 * kpi) * 32 + dblk;
      bf16x4 a = *(const bf16x4*)v0;
      bf16x4 b = *(const bf16x4*)(v0 + 32);
      int keyw = kb * 64 + kpi;
#pragma unroll
      for (int dd = 0; dd < 4; dd++) {
        int row = dblk + dd;
        unsigned wv = (unsigned)__builtin_bit_cast(u16, a[dd]) |
                      ((unsigned)__builtin_bit_cast(u16, b[dd]) << 16);
        *(unsigned*)(sb + ((row * 1024 + keyw * 4) ^ ((row & 7) << 4))) = wv;
      }
    }
  }

  // Q fragments (B operand): lane n=l15 -> query, k=quad*8+j -> d
  bf16x8 qa[2];
#pragma unroll
  for (int nt = 0; nt < 2; nt++)
    qa[nt] = *(const bf16x8*)(qp + (size_t)(qbase + nt * 16 + l15) * 32 + quad * 8);

  // all-ones A-frag for the denominator MFMA
  bf16x8 ones;
#pragma unroll
  for (int e = 0; e < 8; e++) ones[e] = (bf16)1.0f;

  __syncthreads();  // the ONLY block-wide barrier

  f32x4 O[2][2] = {};  // O^T tiles [dm][nt]
  f32x4 O2[2] = {};    // denominator tiles (all rows identical)
  char* pw = (char*)sP[wave];
  const char* sv = (const char*)sVt;
  const int swz = (l15 & 7) << 4;  // row-XOR (same for row and row+16)

#pragma unroll 1
  for (int kt = 0; kt < 8; kt++) {
    // K frags + permuted rpe C-init (in-loop loads; 16 waves/CU hide them)
    bf16x8 kb[4];
    bf16x8 rv8[2][2];  // [nt][half: mt01|mt23]
#pragma unroll
    for (int mt = 0; mt < 4; mt++)
      kb[mt] = *(const bf16x8*)(kp + (size_t)(kt * 64 + mt * 16 + l15) * 32 +
                                quad * 8);
#pragma unroll
    for (int nt = 0; nt < 2; nt++) {
      const bf16* rb =
          rpeh + ((size_t)(kt * 4 + quad) * 512 + (qbase + nt * 16 + l15)) * 16;
      rv8[nt][0] = *(const bf16x8*)rb;
      rv8[nt][1] = *(const bf16x8*)(rb + 8);
    }
    // S^T = K·Q^T with C initialized to fused rpe+mask (pure load)
    f32x4 S[4][2];
#pragma unroll
    for (int mt = 0; mt < 4; mt++)
#pragma unroll
      for (int nt = 0; nt < 2; nt++) {
        f32x4 c;
#pragma unroll
        for (int r = 0; r < 4; r++) c[r] = (float)rv8[nt][mt >> 1][(mt & 1) * 4 + r];
        S[mt][nt] = __builtin_amdgcn_mfma_f32_16x16x32_bf16(kb[mt], qa[nt], c, 0, 0, 0);
      }
    // exp2 + P store (swizzled b64 writes); denominator via MFMA
#pragma unroll
    for (int nt = 0; nt < 2; nt++)
#pragma unroll
      for (int mt = 0; mt < 4; mt++) {
        bf16x4 pv;
#pragma unroll
        for (int r = 0; r < 4; r++) pv[r] = (bf16)exp2f(S[mt][nt][r]);
        *(bf16x4*)(pw + (((nt * 16 + l15) * 128 + mt * 32 + quad * 8) ^ swz)) = pv;
      }
    // O^T += V^T · P ; denominator += ones · P  (sVt read-only; pw per-wave)
#pragma unroll
    for (int s = 0; s < 2; s++) {
      int vc = kt * 128 + s * 64 + quad * 16;  // byte col into V^T row
      int pc = s * 64 + quad * 16;             // byte col into P row
      bf16x8 va0 = *(const bf16x8*)(sv + ((l15 * 1024 + vc) ^ swz));
      bf16x8 va1 = *(const bf16x8*)(sv + (((16 + l15) * 1024 + vc) ^ swz));
      bf16x8 pb0 = *(const bf16x8*)(pw + ((l15 * 128 + pc) ^ swz));
      bf16x8 pb1 = *(const bf16x8*)(pw + (((16 + l15) * 128 + pc) ^ swz));
      O[0][0] = __builtin_amdgcn_mfma_f32_16x16x32_bf16(va0, pb0, O[0][0], 0, 0, 0);
      O[0][1] = __builtin_amdgcn_mfma_f32_16x16x32_bf16(va0, pb1, O[0][1], 0, 0, 0);
      O[1][0] = __builtin_amdgcn_mfma_f32_16x16x32_bf16(va1, pb0, O[1][0], 0, 0, 0);
      O[1][1] = __builtin_amdgcn_mfma_f32_16x16x32_bf16(va1, pb1, O[1][1], 0, 0, 0);
      O2[0] = __builtin_amdgcn_mfma_f32_16x16x32_bf16(ones, pb0, O2[0], 0, 0, 0);
      O2[1] = __builtin_amdgcn_mfma_f32_16x16x32_bf16(ones, pb1, O2[1], 0, 0, 0);
    }
  }
  // epilogue: denominator is in every lane of O2 (no shuffles needed)
#pragma unroll
  for (int nt = 0; nt < 2; nt++) {
    float inv = __builtin_amdgcn_rcpf(O2[nt][0]);
    int q = qbase + nt * 16 + l15;
#pragma unroll
    for (int dm = 0; dm < 2; dm++) {
      bf16x4 o;
#pragma unroll
      for (int r = 0; r < 4; r++) o[r] = (bf16)(O[dm][nt][r] * inv);
      *(bf16x4*)(att + ((size_t)win * 512 + q) * 128 + head * 32 + dm * 16 +
                 quad * 4) = o;
    }
  }
}

// ---------------------------------------------------------------------------
extern "C" void kernel_launch(void* const* d_in, const int* in_sizes, int n_in,
                              void* d_out, int out_size, void* d_ws,
                              size_t ws_size, hipStream_t stream) {
  const int* rel_index = (const int*)d_in[2];
  char* w = (char*)d_ws;

  int* flag = (int*)w;
  bf16* rb_c = (bf16*)(w + (64ull << 10));
  bf16* qw_c = (bf16*)(w + (128ull << 10));
  bf16* pw_c = (bf16*)(w + (256ull << 10));
  bf16* w1_c = (bf16*)(w + (320ull << 10));
  bf16* w2_c = (bf16*)(w + (512ull << 10));
  bf16* qb_c = (bf16*)(w + (704ull << 10));
  bf16* pb_c = (bf16*)(w + (708ull << 10));
  bf16* g1_c = (bf16*)(w + (712ull << 10));
  bf16* b1n_c = (bf16*)(w + (716ull << 10));
  bf16* g2_c = (bf16*)(w + (720ull << 10));
  bf16* b2n_c = (bf16*)(w + (724ull << 10));
  bf16* mb1_c = (bf16*)(w + (728ull << 10));
  bf16* mb2_c = (bf16*)(w + (732ull << 10));
  bf16* xw = (bf16*)(w + (17ull << 20));    // [17,33) MB; reused: att, h2
  bf16* qkvb = (bf16*)(w + (33ull << 20));  // [33,97) MB; reused: a1
  bf16* x2 = (bf16*)(w + (99ull << 20));    // [99,115) MB; rpem lives here
  bf16* rpem = x2;  // 16 MiB fused rpe+mask planes; dead before proj writes x2
  bf16* att = xw;
  bf16* h2 = xw;
  bf16* a1 = qkvb;

  sniff_k<<<1, 64, 0, stream>>>((const unsigned*)d_in[0], flag);

  CanonArgs ca;
  const int srcidx[13] = {3, 4, 5, 6, 7, 8, 9, 10, 11, 12, 13, 14, 15};
  bf16* dsts[13] = {rb_c, qw_c, qb_c, pw_c, pb_c, g1_c, b1n_c,
                    g2_c, b2n_c, w1_c, mb1_c, w2_c, mb2_c};
  for (int i = 0; i < 13; i++) {
    ca.src[i] = d_in[srcidx[i]];
    ca.dst[i] = dsts[i];
    ca.n[i] = in_sizes[srcidx[i]];
  }
  canon_small_k<<<dim3(256, 13), 256, 0, stream>>>(ca, flag);

  rpem_k<<<8192, 256, 0, stream>>>(rel_index, rb_c, rpem);
  // LN1 reads RAW input (canon_big fused away)
  ln_k<1><<<16384, 256, 0, stream>>>(d_in[0], g1_c, b1n_c, xw, flag);
  gemm_k<0, 64, 128, 384, 128><<<dim3(1024, 3), 256, 0, stream>>>(
      xw, qw_c, qb_c, qkvb, nullptr, flag);
  attn_k<<<1024, 512, 0, stream>>>(qkvb, rpem, att);
  // proj resid = RAW input (flag-dispatched dtype)
  gemm_k<1, 64, 128, 128, 128><<<dim3(1024, 1), 256, 0, stream>>>(
      att, pw_c, pb_c, x2, d_in[0], flag);
  ln_k<0><<<16384, 256, 0, stream>>>(x2, g2_c, b2n_c, h2, flag);
  gemm_k<2, 64, 128, 512, 128><<<dim3(1024, 4), 256, 0, stream>>>(
      h2, w1_c, mb1_c, a1, nullptr, flag);
  gemm_k<3, 64, 64, 128, 512><<<dim3(1024, 1), 256, 0, stream>>>(
      a1, w2_c, mb2_c, d_out, x2, flag);
}

// Round 7
// 384.948 us; speedup vs baseline: 1.1991x; 1.0135x over previous
//
#include <hip/hip_runtime.h>
#include <math.h>

typedef __bf16 bf16;
typedef __bf16 bf16x4 __attribute__((ext_vector_type(4)));
typedef __bf16 bf16x8 __attribute__((ext_vector_type(8)));
typedef float f32x4 __attribute__((ext_vector_type(4)));
typedef unsigned short u16;
typedef u16 u16x2 __attribute__((ext_vector_type(2)));

#define LOG2E 1.4426950408889634f

__device__ __forceinline__ float b2f(u16 b) {
  return (float)__builtin_bit_cast(bf16, b);
}

// ---------------------------------------------------------------------------
// dtype sniff (wave-parallel): packed-bf16 words have bits14..7 = bf16
// exponent (~[118,130]); f32 words have uniform mantissa bits there.
// ---------------------------------------------------------------------------
__global__ void sniff_k(const unsigned* __restrict__ xw_, int* __restrict__ flag) {
  int lane = threadIdx.x;  // 64 threads
  int c = 0;
#pragma unroll
  for (int j = 0; j < 4; j++) {
    unsigned e = (xw_[lane * 4 + j] >> 7) & 0xFFu;
    c += (e >= 100u && e <= 140u) ? 1 : 0;
  }
#pragma unroll
  for (int d = 1; d < 64; d <<= 1) c += __shfl_xor(c, d);
  if (lane == 0) *flag = (c >= 150) ? 1 : 0;
}

// ---------------------------------------------------------------------------
// Fused prologue: one launch, three block-segments (R7):
//   [0,8192)      rpem: fused rpe+mask planes, PERMUTED layout, RAW rel_bias
//   [8192,24576)  ln1: LN + roll(-4) + window partition, RAW input
//   [24576,27648) canon: 12 small weight tensors -> bf16
// All segments read *flag (sniff_k runs first).
// rpem plane[type][h] is [kt:8][quad:4][q:512][mt:4][r:4]; value =
// rel_bias[rel_index[q*512+m]][h]*log2e + (masked?-100*log2e:0).
// ---------------------------------------------------------------------------
struct ProArgs {
  const int* ridx;
  const void* rbias;
  bf16* rpem;
  const void* x;
  const bf16* g1;
  const bf16* b1n;
  bf16* xw;
  const void* csrc[12];
  bf16* cdst[12];
  int cn[12];
};

__global__ __launch_bounds__(256) void pro_k(ProArgs a,
                                             const int* __restrict__ flag) {
  const int bx = blockIdx.x, tid = threadIdx.x;
  const int fl = *flag;
  if (bx < 8192) {  // ---- rpem ----
    int t = bx * 256 + tid;  // 2^21 threads, 4 m-values each
    int m0 = (t & 127) * 4, q = (t >> 7) & 511, h = (t >> 16) & 3, ty = t >> 18;
    int qd = q >> 6, qh = (q >> 3) & 7, qw = q & 7;
    int kt = m0 >> 6, mt = (m0 >> 4) & 3, quad = (m0 >> 2) & 3;
    int4 ri = *(const int4*)&a.ridx[q * 512 + m0];
    const int rv[4] = {ri.x, ri.y, ri.z, ri.w};
    bf16x4 o;
#pragma unroll
    for (int j = 0; j < 4; j++) {
      int m = m0 + j;
      int md = m >> 6, mh = (m >> 3) & 7, mw = m & 7;
      bool diff = ((ty & 4) && ((qd < 4) != (md < 4))) ||
                  ((ty & 2) && ((qh < 4) != (mh < 4))) ||
                  ((ty & 1) && ((qw < 4) != (mw < 4)));
      float bv = fl ? (float)((const bf16*)a.rbias)[rv[j] * 4 + h]
                    : ((const float*)a.rbias)[rv[j] * 4 + h];
      float v = bv * LOG2E;
      o[j] = (bf16)(v + (diff ? -144.2695041f : 0.f));
    }
    size_t out = ((size_t)(ty * 4 + h) << 18) +
                 (((size_t)(kt * 4 + quad) * 512 + q) * 16 + mt * 4);
    *(bf16x4*)&a.rpem[out] = o;
  } else if (bx < 24576) {  // ---- ln1 (roll + window partition) ----
    int wave = tid >> 6, lane = tid & 63;
    int tok = (bx - 8192) * 4 + wave;
    int win = tok >> 9, pos = tok & 511;
    int rd = (win >> 6) * 8 + (pos >> 6);
    int rh = ((win >> 3) & 7) * 8 + ((pos >> 3) & 7);
    int rw = (win & 7) * 8 + (pos & 7);
    int od = (rd + 4) & 15, oh = (rh + 4) & 63, ow = (rw + 4) & 63;
    size_t src = (size_t)((od * 64 + oh) * 64 + ow) * 128;
    int ch = lane * 2;
    float f0, f1;
    if (!fl) {
      const float* xf = (const float*)a.x + src + ch;
      f0 = xf[0];
      f1 = xf[1];
    } else {
      u16x2 xv = *(const u16x2*)((const bf16*)a.x + src + ch);
      f0 = b2f(xv[0]);
      f1 = b2f(xv[1]);
    }
    float s = f0 + f1, sq = f0 * f0 + f1 * f1;
#pragma unroll
    for (int d = 1; d < 64; d <<= 1) {
      s += __shfl_xor(s, d);
      sq += __shfl_xor(sq, d);
    }
    float mean = s * (1.f / 128.f);
    float var = sq * (1.f / 128.f) - mean * mean;
    float rstd = rsqrtf(fmaxf(var, 0.f) + 1e-5f);
    u16x2 gv = *(const u16x2*)(a.g1 + ch), bv = *(const u16x2*)(a.b1n + ch);
    u16x2 ov;
    ov[0] =
        __builtin_bit_cast(u16, (bf16)((f0 - mean) * rstd * b2f(gv[0]) + b2f(bv[0])));
    ov[1] =
        __builtin_bit_cast(u16, (bf16)((f1 - mean) * rstd * b2f(gv[1]) + b2f(bv[1])));
    *(u16x2*)(a.xw + (size_t)tok * 128 + ch) = ov;
  } else {  // ---- canon ----
    int seg = bx - 24576;
    int ti = seg >> 8;
    int i = (seg & 255) * 256 + tid;
    if (i < a.cn[ti]) {
      if (fl)
        a.cdst[ti][i] = ((const bf16*)a.csrc[ti])[i];
      else
        a.cdst[ti][i] = (bf16)((const float*)a.csrc[ti])[i];
    }
  }
}

// ---------------------------------------------------------------------------
// LayerNorm, linear bf16 in/out (ln2). One wave per token (C=128).
// ---------------------------------------------------------------------------
__global__ __launch_bounds__(256) void ln_k(const bf16* __restrict__ x,
                                            const bf16* __restrict__ g,
                                            const bf16* __restrict__ bsh,
                                            bf16* __restrict__ out) {
  int wave = threadIdx.x >> 6, lane = threadIdx.x & 63;
  int tok = blockIdx.x * 4 + wave;
  size_t src = (size_t)tok * 128;
  int ch = lane * 2;
  u16x2 xv = *(const u16x2*)(x + src + ch);
  float f0 = b2f(xv[0]), f1 = b2f(xv[1]);
  float s = f0 + f1, sq = f0 * f0 + f1 * f1;
#pragma unroll
  for (int d = 1; d < 64; d <<= 1) {
    s += __shfl_xor(s, d);
    sq += __shfl_xor(sq, d);
  }
  float mean = s * (1.f / 128.f);
  float var = sq * (1.f / 128.f) - mean * mean;
  float rstd = rsqrtf(fmaxf(var, 0.f) + 1e-5f);
  u16x2 gv = *(const u16x2*)(g + ch), bv = *(const u16x2*)(bsh + ch);
  u16x2 ov;
  ov[0] = __builtin_bit_cast(u16, (bf16)((f0 - mean) * rstd * b2f(gv[0]) + b2f(bv[0])));
  ov[1] = __builtin_bit_cast(u16, (bf16)((f1 - mean) * rstd * b2f(gv[1]) + b2f(bv[1])));
  *(u16x2*)(out + (size_t)tok * 128 + ch) = ov;
}

// ---------------------------------------------------------------------------
// bf16 MFMA GEMM: C[M,N] = A[M,K] @ B[N,K]^T + bias[N] (+ epilogue)
// R13: BM=32 for the K=128 GEMMs -> LDS 40 KB -> 4 blocks/CU (R5/R6: these
// are latency-bound; co-resident stages are the lever). Single-stage BK=128.
// global_load_lds width=16, linear LDS dest, inverse-XOR-swizzled global
// source, XOR on ds_read. Direct-store epilogue.
// EPI: 0 = qkv (q scale*log2e, head-major scatter), 1 = proj (win-rev+roll+
//      RAW-resid via flag)
// ---------------------------------------------------------------------------
template <int EPI, int BM, int BK, int N_, int K_>
__global__ __launch_bounds__(256) void gemm_k(const bf16* __restrict__ A,
                                              const bf16* __restrict__ B,
                                              const bf16* __restrict__ bias,
                                              void* __restrict__ outv,
                                              const void* __restrict__ residv,
                                              const int* __restrict__ flag) {
  constexpr int NC = K_ / BK;
  constexpr int NBUF = (NC > 1) ? 2 : 1;
  __shared__ __align__(16) u16 SM[NBUF][(BM + 128) * BK];
  const int t = threadIdx.x;
  const int wave = t >> 6, lane = t & 63, l15 = lane & 15, quad = lane >> 4;
  const int m0 = blockIdx.x * BM, n0 = blockIdx.y * 128;
  constexpr int MI = BM / 32;  // m-frags per wave
  int fl = 0;
  if constexpr (EPI == 1) fl = *flag;
  f32x4 acc[MI][4] = {};
  const int wr = (wave >> 1) * (BM / 2), wc = (wave & 1) * 64;
  constexpr int TPR = BK / 8;     // 16B chunks per row
  constexpr int RPP = 256 / TPR;  // rows staged per 256-thread pass
  constexpr int PASSES = (BM + 128) / RPP;
  const int srow = t / TPR, sc16 = t % TPR;

  auto stage = [&](int c, int buf) {
#pragma unroll
    for (int p = 0; p < PASSES; p++) {
      int row = p * RPP + srow;
      int cs = sc16 ^ (row & 7);
      const u16* src;
      if (row < BM)
        src = (const u16*)A + (size_t)(m0 + row) * K_ + c * BK + cs * 8;
      else
        src = (const u16*)B + (size_t)(n0 + row - BM) * K_ + c * BK + cs * 8;
      __builtin_amdgcn_global_load_lds(
          (const __attribute__((address_space(1))) void*)src,
          (__attribute__((address_space(3))) void*)&SM[buf][row * BK + sc16 * 8],
          16, 0, 0);
    }
  };

  stage(0, 0);
  __syncthreads();  // vmcnt(0) drain + barrier: buf0 fully staged
#pragma unroll
  for (int c = 0; c < NC; c++) {
    if (c + 1 < NC) stage(c + 1, (c + 1) & 1);
    const char* cur = (const char*)SM[c & 1];
#pragma unroll
    for (int ks = 0; ks < BK / 32; ks++) {
      bf16x8 a[MI], b[4];
#pragma unroll
      for (int i = 0; i < MI; i++) {
        int row = wr + i * 16 + l15;
        a[i] = *(const bf16x8*)(cur + row * (BK * 2) +
                                (((ks * 4 + quad) ^ (row & 7)) << 4));
      }
#pragma unroll
      for (int j = 0; j < 4; j++) {
        int row = BM + wc + j * 16 + l15;
        b[j] = *(const bf16x8*)(cur + row * (BK * 2) +
                                (((ks * 4 + quad) ^ (row & 7)) << 4));
      }
#pragma unroll
      for (int i = 0; i < MI; i++)
#pragma unroll
        for (int j = 0; j < 4; j++)
          acc[i][j] =
              __builtin_amdgcn_mfma_f32_16x16x32_bf16(a[i], b[j], acc[i][j], 0, 0, 0);
    }
    if (c + 1 < NC) __syncthreads();
  }
  // q scale folded with log2e for exp2-domain softmax downstream
  const float qscale = 0.17677669529663687f * LOG2E;
#pragma unroll
  for (int i = 0; i < MI; i++) {
#pragma unroll
    for (int r = 0; r < 4; r++) {
      int tok = m0 + wr + i * 16 + quad * 4 + r;
      size_t obase = 0;
      if constexpr (EPI == 1) {
        int win = tok >> 9, pos = tok & 511;
        int rd = (win >> 6) * 8 + (pos >> 6);
        int rh = ((win >> 3) & 7) * 8 + ((pos >> 3) & 7);
        int rw = (win & 7) * 8 + (pos & 7);
        int od = (rd + 4) & 15, oh = (rh + 4) & 63, ow = (rw + 4) & 63;
        obase = (size_t)((od * 64 + oh) * 64 + ow) * 128;
      }
#pragma unroll
      for (int j = 0; j < 4; j++) {
        int gn = n0 + wc + j * 16 + l15;
        float v = acc[i][j][r] + (float)bias[gn];
        if constexpr (EPI == 0) {
          int tensor = gn >> 7, c = gn & 127, head = c >> 5, d = c & 31;
          if (tensor == 0) v *= qscale;
          int win = tok >> 9, pos = tok & 511;
          size_t off = ((((size_t)tensor * 4 + head) * 128 + win) * 512 + pos) * 32 + d;
          ((bf16*)outv)[off] = (bf16)v;
        } else {
          // proj: resid = RAW input (flag-dispatched dtype), win-rev+roll out
          float rs = fl ? (float)((const bf16*)residv)[obase + gn]
                        : ((const float*)residv)[obase + gn];
          v += rs;
          ((bf16*)outv)[obase + gn] = (bf16)v;
        }
      }
    }
  }
}

// ---------------------------------------------------------------------------
// Fused MLP (R7): per 32-token block, h1 = gelu(h2 @ W1^T + b1) is computed
// chunk-by-chunk into a 33 KB LDS tile (never touches HBM — kills the 64 MB
// a1 intermediate), then out = h1 @ W2^T + b2 + resid contracted K=512 with
// W2 streamed through the same 32 KB staging buffer. LDS 74 KB -> 2 blk/CU.
// ---------------------------------------------------------------------------
__global__ __launch_bounds__(256) void mlp_k(const bf16* __restrict__ A,
                                             const bf16* __restrict__ W1,
                                             const bf16* __restrict__ B1,
                                             const bf16* __restrict__ W2,
                                             const bf16* __restrict__ B2,
                                             const bf16* __restrict__ resid,
                                             void* __restrict__ outv,
                                             const int* __restrict__ flag) {
  __shared__ __align__(16) u16 sA[32 * 128];   // h2 tile, swizzled
  __shared__ __align__(16) u16 sB[128 * 128];  // w1/w2 chunk, swizzled
  __shared__ __align__(16) u16 sH[32 * 520];   // gelu(h1) tile, padded
  const int t = threadIdx.x;
  const int wave = t >> 6, lane = t & 63, l15 = lane & 15, quad = lane >> 4;
  const int m0 = blockIdx.x * 32;
  const int wr = (wave >> 1) * 16, wc = (wave & 1) * 64;
  const int fl = *flag;
  const int srow = t >> 4, sc16 = t & 15;

  auto stage_w = [&](const bf16* W, int chunk, int wK) {
#pragma unroll
    for (int p = 0; p < 8; p++) {
      int row = p * 16 + srow;  // 0..127
      int cs = sc16 ^ (row & 7);
      const u16* src = (const u16*)W + (size_t)(wK == 128 ? (chunk * 128 + row) : row) *
                                           wK +
                       (wK == 128 ? 0 : chunk * 128) + cs * 8;
      __builtin_amdgcn_global_load_lds(
          (const __attribute__((address_space(1))) void*)src,
          (__attribute__((address_space(3))) void*)&sB[row * 128 + sc16 * 8], 16,
          0, 0);
    }
  };

  {  // stage h2 tile: 32 rows x 16 chunks = 2 passes
#pragma unroll
    for (int p = 0; p < 2; p++) {
      int row = p * 16 + srow;
      int cs = sc16 ^ (row & 7);
      __builtin_amdgcn_global_load_lds(
          (const __attribute__((address_space(1))) void*)((const u16*)A +
                                                          (size_t)(m0 + row) * 128 +
                                                          cs * 8),
          (__attribute__((address_space(3))) void*)&sA[row * 128 + sc16 * 8], 16,
          0, 0);
    }
  }
  stage_w(W1, 0, 128);
  __syncthreads();

  // ---- mlp1: 4 n-chunks of 128, gelu into sH ----
#pragma unroll 1
  for (int nc = 0; nc < 4; nc++) {
    f32x4 acc1[4] = {};
#pragma unroll
    for (int ks = 0; ks < 4; ks++) {
      int arow = wr + l15;
      bf16x8 av = *(const bf16x8*)((const char*)sA + arow * 256 +
                                   (((ks * 4 + quad) ^ (arow & 7)) << 4));
      bf16x8 bv[4];
#pragma unroll
      for (int j = 0; j < 4; j++) {
        int row = wc + j * 16 + l15;
        bv[j] = *(const bf16x8*)((const char*)sB + row * 256 +
                                 (((ks * 4 + quad) ^ (row & 7)) << 4));
      }
#pragma unroll
      for (int j = 0; j < 4; j++)
        acc1[j] = __builtin_amdgcn_mfma_f32_16x16x32_bf16(av, bv[j], acc1[j], 0, 0, 0);
    }
#pragma unroll
    for (int j = 0; j < 4; j++) {
      int ncol = nc * 128 + wc + j * 16 + l15;
      float bj = (float)B1[ncol];
#pragma unroll
      for (int r = 0; r < 4; r++) {
        float v = acc1[j][r] + bj;
        float v2 = v * v;
        float u2 = v * (2.30220806f + 0.10294323f * v2);
        float e2 = exp2f(u2);
        v = v - v * __builtin_amdgcn_rcpf(e2 + 1.f);
        sH[(wr + quad * 4 + r) * 520 + ncol] = __builtin_bit_cast(u16, (bf16)v);
      }
    }
    __syncthreads();  // sB reads + sH writes done
    if (nc < 3)
      stage_w(W1, nc + 1, 128);
    else
      stage_w(W2, 0, 512);
    __syncthreads();  // staged
  }

  // ---- mlp2: contract K=512 from sH against streamed W2 chunks ----
  f32x4 acc2[4] = {};
#pragma unroll 1
  for (int kc = 0; kc < 4; kc++) {
#pragma unroll
    for (int ks = 0; ks < 4; ks++) {
      int arow = wr + l15;
      bf16x8 av = *(const bf16x8*)((const char*)sH + arow * 1040 +
                                   (kc * 128 + ks * 32 + quad * 8) * 2);
      bf16x8 bv[4];
#pragma unroll
      for (int j = 0; j < 4; j++) {
        int row = wc + j * 16 + l15;
        bv[j] = *(const bf16x8*)((const char*)sB + row * 256 +
                                 (((ks * 4 + quad) ^ (row & 7)) << 4));
      }
#pragma unroll
      for (int j = 0; j < 4; j++)
        acc2[j] = __builtin_amdgcn_mfma_f32_16x16x32_bf16(av, bv[j], acc2[j], 0, 0, 0);
    }
    if (kc < 3) {
      __syncthreads();
      stage_w(W2, kc + 1, 512);
      __syncthreads();
    }
  }
  // ---- epilogue: +b2 +resid, flag-dispatched output dtype ----
#pragma unroll
  for (int j = 0; j < 4; j++) {
    int gn = wc + j * 16 + l15;
    float bj = (float)B2[gn];
#pragma unroll
    for (int r = 0; r < 4; r++) {
      int tok = m0 + wr + quad * 4 + r;
      size_t off = (size_t)tok * 128 + gn;
      float v = acc2[j][r] + bj + (float)resid[off];
      if (fl)
        ((bf16*)outv)[off] = (bf16)v;
      else
        ((float*)outv)[off] = v;
    }
  }
}

// ---------------------------------------------------------------------------
// Fused window attention, S^T formulation, exp2-domain, BARRIER-FREE K-loop.
// R6 structure unchanged (best measured): 8-wave shared-V (64 KB LDS,
// 2 blocks/CU), denominator on the MFMA pipe (ones-frag), XOR-swizzled LDS,
// permuted-rpem coalesced b128 C-init, #pragma unroll 1 in-loop loads.
// ---------------------------------------------------------------------------
__global__ __launch_bounds__(512, 4) void attn_k(const bf16* __restrict__ qkv,
                                                 const bf16* __restrict__ rpem,
                                                 bf16* __restrict__ att) {
  __shared__ __align__(16) bf16 sVt[32 * 512];   // V^T [d][key], swizzled, 32 KB
  __shared__ __align__(16) bf16 sP[8][32 * 64];  // per-wave P^T, swizzled, 32 KB
  const int t = threadIdx.x;
  const int p = blockIdx.x;  // [win_hi:4][head:2][qh:1][win_lo:3]
  const int win = ((p >> 6) << 3) | (p & 7);
  const int mid = (p >> 3) & 7;
  const int head = mid >> 1, qh = mid & 1;
  const int wave = t >> 6, lane = t & 63, l15 = lane & 15, quad = lane >> 4;

  const int wd = win >> 6, wh = (win >> 3) & 7, ww = win & 7;
  const int type = ((wd == 1) << 2) | ((wh == 7) << 1) | (ww == 7);

  const size_t hw32 = (size_t)512 * 32;
  const bf16* qp = qkv + ((size_t)(0 * 4 + head) * 128 + win) * hw32;
  const bf16* kp = qkv + ((size_t)(1 * 4 + head) * 128 + win) * hw32;
  const bf16* vp = qkv + ((size_t)(2 * 4 + head) * 128 + win) * hw32;
  const bf16* rpeh = rpem + ((size_t)(type * 4 + head) << 18);
  const int qbase = qh * 256 + wave * 32;

  {  // stage full V^T once (512 threads), XOR-swizzled u32 writes
    int kpi = t >> 3, dblk = (t & 7) * 4;
    char* sb = (char*)sVt;
#pragma unroll
    for (int kb = 0; kb < 4; kb++) {
      const bf16* v0 = vp + (size_t)(kb * 128 + 2 * kpi) * 32 + dblk;
      bf16x4 a = *(const bf16x4*)v0;
      bf16x4 b = *(const bf16x4*)(v0 + 32);
      int keyw = kb * 64 + kpi;
#pragma unroll
      for (int dd = 0; dd < 4; dd++) {
        int row = dblk + dd;
        unsigned wv = (unsigned)__builtin_bit_cast(u16, a[dd]) |
                      ((unsigned)__builtin_bit_cast(u16, b[dd]) << 16);
        *(unsigned*)(sb + ((row * 1024 + keyw * 4) ^ ((row & 7) << 4))) = wv;
      }
    }
  }

  // Q fragments (B operand): lane n=l15 -> query, k=quad*8+j -> d
  bf16x8 qa[2];
#pragma unroll
  for (int nt = 0; nt < 2; nt++)
    qa[nt] = *(const bf16x8*)(qp + (size_t)(qbase + nt * 16 + l15) * 32 + quad * 8);

  // all-ones A-frag for the denominator MFMA
  bf16x8 ones;
#pragma unroll
  for (int e = 0; e < 8; e++) ones[e] = (bf16)1.0f;

  __syncthreads();  // the ONLY block-wide barrier

  f32x4 O[2][2] = {};  // O^T tiles [dm][nt]
  f32x4 O2[2] = {};    // denominator tiles (all rows identical)
  char* pw = (char*)sP[wave];
  const char* sv = (const char*)sVt;
  const int swz = (l15 & 7) << 4;  // row-XOR (same for row and row+16)

#pragma unroll 1
  for (int kt = 0; kt < 8; kt++) {
    // K frags + permuted rpe C-init (in-loop loads; 16 waves/CU hide them)
    bf16x8 kb[4];
    bf16x8 rv8[2][2];  // [nt][half: mt01|mt23]
#pragma unroll
    for (int mt = 0; mt < 4; mt++)
      kb[mt] = *(const bf16x8*)(kp + (size_t)(kt * 64 + mt * 16 + l15) * 32 +
                                quad * 8);
#pragma unroll
    for (int nt = 0; nt < 2; nt++) {
      const bf16* rb =
          rpeh + ((size_t)(kt * 4 + quad) * 512 + (qbase + nt * 16 + l15)) * 16;
      rv8[nt][0] = *(const bf16x8*)rb;
      rv8[nt][1] = *(const bf16x8*)(rb + 8);
    }
    // S^T = K·Q^T with C initialized to fused rpe+mask (pure load)
    f32x4 S[4][2];
#pragma unroll
    for (int mt = 0; mt < 4; mt++)
#pragma unroll
      for (int nt = 0; nt < 2; nt++) {
        f32x4 c;
#pragma unroll
        for (int r = 0; r < 4; r++) c[r] = (float)rv8[nt][mt >> 1][(mt & 1) * 4 + r];
        S[mt][nt] = __builtin_amdgcn_mfma_f32_16x16x32_bf16(kb[mt], qa[nt], c, 0, 0, 0);
      }
    // exp2 + P store (swizzled b64 writes); denominator via MFMA
#pragma unroll
    for (int nt = 0; nt < 2; nt++)
#pragma unroll
      for (int mt = 0; mt < 4; mt++) {
        bf16x4 pv;
#pragma unroll
        for (int r = 0; r < 4; r++) pv[r] = (bf16)exp2f(S[mt][nt][r]);
        *(bf16x4*)(pw + (((nt * 16 + l15) * 128 + mt * 32 + quad * 8) ^ swz)) = pv;
      }
    // O^T += V^T · P ; denominator += ones · P  (sVt read-only; pw per-wave)
#pragma unroll
    for (int s = 0; s < 2; s++) {
      int vc = kt * 128 + s * 64 + quad * 16;  // byte col into V^T row
      int pc = s * 64 + quad * 16;             // byte col into P row
      bf16x8 va0 = *(const bf16x8*)(sv + ((l15 * 1024 + vc) ^ swz));
      bf16x8 va1 = *(const bf16x8*)(sv + (((16 + l15) * 1024 + vc) ^ swz));
      bf16x8 pb0 = *(const bf16x8*)(pw + ((l15 * 128 + pc) ^ swz));
      bf16x8 pb1 = *(const bf16x8*)(pw + (((16 + l15) * 128 + pc) ^ swz));
      O[0][0] = __builtin_amdgcn_mfma_f32_16x16x32_bf16(va0, pb0, O[0][0], 0, 0, 0);
      O[0][1] = __builtin_amdgcn_mfma_f32_16x16x32_bf16(va0, pb1, O[0][1], 0, 0, 0);
      O[1][0] = __builtin_amdgcn_mfma_f32_16x16x32_bf16(va1, pb0, O[1][0], 0, 0, 0);
      O[1][1] = __builtin_amdgcn_mfma_f32_16x16x32_bf16(va1, pb1, O[1][1], 0, 0, 0);
      O2[0] = __builtin_amdgcn_mfma_f32_16x16x32_bf16(ones, pb0, O2[0], 0, 0, 0);
      O2[1] = __builtin_amdgcn_mfma_f32_16x16x32_bf16(ones, pb1, O2[1], 0, 0, 0);
    }
  }
  // epilogue: denominator is in every lane of O2 (no shuffles needed)
#pragma unroll
  for (int nt = 0; nt < 2; nt++) {
    float inv = __builtin_amdgcn_rcpf(O2[nt][0]);
    int q = qbase + nt * 16 + l15;
#pragma unroll
    for (int dm = 0; dm < 2; dm++) {
      bf16x4 o;
#pragma unroll
      for (int r = 0; r < 4; r++) o[r] = (bf16)(O[dm][nt][r] * inv);
      *(bf16x4*)(att + ((size_t)win * 512 + q) * 128 + head * 32 + dm * 16 +
                 quad * 4) = o;
    }
  }
}

// ---------------------------------------------------------------------------
extern "C" void kernel_launch(void* const* d_in, const int* in_sizes, int n_in,
                              void* d_out, int out_size, void* d_ws,
                              size_t ws_size, hipStream_t stream) {
  const int* rel_index = (const int*)d_in[2];
  char* w = (char*)d_ws;

  int* flag = (int*)w;
  bf16* qw_c = (bf16*)(w + (128ull << 10));
  bf16* pw_c = (bf16*)(w + (256ull << 10));
  bf16* w1_c = (bf16*)(w + (320ull << 10));
  bf16* w2_c = (bf16*)(w + (512ull << 10));
  bf16* qb_c = (bf16*)(w + (704ull << 10));
  bf16* pb_c = (bf16*)(w + (708ull << 10));
  bf16* g1_c = (bf16*)(w + (712ull << 10));
  bf16* b1n_c = (bf16*)(w + (716ull << 10));
  bf16* g2_c = (bf16*)(w + (720ull << 10));
  bf16* b2n_c = (bf16*)(w + (724ull << 10));
  bf16* mb1_c = (bf16*)(w + (728ull << 10));
  bf16* mb2_c = (bf16*)(w + (732ull << 10));
  bf16* xw = (bf16*)(w + (17ull << 20));    // [17,33) MB; reused: att, h2
  bf16* qkvb = (bf16*)(w + (33ull << 20));  // [33,97) MB
  bf16* x2 = (bf16*)(w + (99ull << 20));    // [99,115) MB; rpem lives here
  bf16* rpem = x2;  // 16 MiB fused rpe+mask planes; dead before proj writes x2
  bf16* att = xw;
  bf16* h2 = xw;

  sniff_k<<<1, 64, 0, stream>>>((const unsigned*)d_in[0], flag);

  ProArgs pa;
  pa.ridx = rel_index;
  pa.rbias = d_in[3];
  pa.rpem = rpem;
  pa.x = d_in[0];
  pa.g1 = g1_c;
  pa.b1n = b1n_c;
  pa.xw = xw;
  const int srcidx[12] = {4, 5, 6, 7, 8, 9, 10, 11, 12, 13, 14, 15};
  bf16* dsts[12] = {qw_c, qb_c, pw_c, pb_c, g1_c, b1n_c,
                    g2_c, b2n_c, w1_c, mb1_c, w2_c, mb2_c};
  for (int i = 0; i < 12; i++) {
    pa.csrc[i] = d_in[srcidx[i]];
    pa.cdst[i] = dsts[i];
    pa.cn[i] = in_sizes[srcidx[i]];
  }
  // NOTE: pro_k's ln1 segment reads g1_c/b1n_c which its canon segment
  // writes — but ln1 multiplies by gamma AFTER the reduction; the canon
  // segment (3072 tiny blocks) is dispatched last yet there is no intra-
  // kernel ordering guarantee. To be safe, canon norm params FIRST via a
  // dedicated micro-launch before pro_k.
  {
    CanonFix:;
  }
  struct NormFixArgs {
    const void* s[4];
    bf16* d[4];
  };
  // canon the 4 LN params (g1,b1n,g2,b2n) in sniff's shadow: tiny kernel
  // (512 elems) — avoids the pro_k intra-kernel dependency.
  auto canon_norm = [&]() {};
  (void)canon_norm;
  {
    // reuse canon segment of pro_k is unsafe for g1/b1n only; launch a
    // 2-block helper using canon_small-style copy for indices 8,9.
    struct MiniArgs {
      const void* src[2];
      bf16* dst[2];
      int n[2];
    };
    static_assert(sizeof(MiniArgs) <= 64, "");
  }
  // Simple + safe: small dedicated kernel for g1/b1n.
  {
    ProArgs dummy = pa;
    (void)dummy;
  }
  // launch helper implemented via pro_k's canon segment only for g1/b1n:
  // a 2-block pro_k-style launch would need a separate kernel; instead use
  // hipMemcpyAsync-free micro canon below.
  {
    // ln params are 128 elems each; one 256-thread block handles both.
  }
  extern __global__ void canon_norm_k(const void*, const void*, bf16*, bf16*,
                                      const int*);
  canon_norm_k<<<1, 256, 0, stream>>>(d_in[8], d_in[9], g1_c, b1n_c, flag);

  pro_k<<<27648, 256, 0, stream>>>(pa, flag);
  gemm_k<0, 32, 128, 384, 128><<<dim3(2048, 3), 256, 0, stream>>>(
      xw, qw_c, qb_c, qkvb, nullptr, flag);
  attn_k<<<1024, 512, 0, stream>>>(qkvb, rpem, att);
  gemm_k<1, 32, 128, 128, 128><<<dim3(2048, 1), 256, 0, stream>>>(
      att, pw_c, pb_c, x2, d_in[0], flag);
  ln_k<<<16384, 256, 0, stream>>>(x2, g2_c, b2n_c, h2);
  mlp_k<<<2048, 256, 0, stream>>>(h2, w1_c, mb1_c, w2_c, mb2_c, x2, d_out, flag);
}

// canon g1/b1n ahead of pro_k (pro_k's ln1 segment consumes them; intra-
// kernel block ordering is undefined, so they must be ready beforehand).
__global__ __launch_bounds__(256) void canon_norm_k(
    const void* __restrict__ sg, const void* __restrict__ sb,
    bf16* __restrict__ dg, bf16* __restrict__ db, const int* __restrict__ flag) {
  int i = threadIdx.x;  // 256 threads, 128 elems each tensor
  int fl = *flag;
  if (i < 128) {
    dg[i] = fl ? ((const bf16*)sg)[i] : (bf16)((const float*)sg)[i];
  } else {
    int j = i - 128;
    db[j] = fl ? ((const bf16*)sb)[j] : (bf16)((const float*)sb)[j];
  }
}